// Round 3
// baseline (1463.488 us; speedup 1.0000x reference)
//
#include <hip/hip_runtime.h>
#include <math.h>

#define Tt 1024
#define Dd 1024
#define Hh 16
#define DHh 64
#define MAXPOS 64
#define BTt 2048

// ---------------- VALU GEMM: C[M,N] = A[M,K] * W[N,K]^T + bias (fp32) -----------
#define GBM 128
#define GBN 128
#define GBK 16

__device__ __forceinline__ void gemm_body(const float* __restrict__ A,
                                          const float* __restrict__ W,
                                          const float* __restrict__ bias,
                                          float* __restrict__ C,
                                          int M, int N, int K)
{
    __shared__ float As[GBM][GBK + 1];
    __shared__ float Bs[GBN][GBK + 1];
    const int t = threadIdx.x;
    const int tx = t & 15, ty = t >> 4;     // 16 x 16 thread grid
    const int row0 = blockIdx.x * GBM, col0 = blockIdx.y * GBN;

    float acc[8][8];
    for (int r = 0; r < 8; ++r)
        for (int c = 0; c < 8; ++c) acc[r][c] = 0.f;

    for (int kb = 0; kb < K; kb += GBK) {
        __syncthreads();
        for (int s = 0; s < 8; ++s) {
            int idx = t * 8 + s;            // 0..2047 = 128 rows x 16 cols
            int r = idx >> 4, c = idx & 15;
            As[r][c] = A[(size_t)(row0 + r) * K + kb + c];
            Bs[r][c] = W[(size_t)(col0 + r) * K + kb + c];
        }
        __syncthreads();
        for (int kk = 0; kk < GBK; ++kk) {
            float av[8], bv[8];
            for (int r = 0; r < 8; ++r) av[r] = As[ty * 8 + r][kk];
            for (int c = 0; c < 8; ++c) bv[c] = Bs[tx * 8 + c][kk];
            for (int r = 0; r < 8; ++r)
                for (int c = 0; c < 8; ++c)
                    acc[r][c] += av[r] * bv[c];
        }
    }
    for (int r = 0; r < 8; ++r) {
        int row = row0 + ty * 8 + r;
        for (int c = 0; c < 8; ++c) {
            int col = col0 + tx * 8 + c;
            C[(size_t)row * N + col] = acc[r][c] + bias[col];
        }
    }
}

__global__ __launch_bounds__(256) void gemm_qkv(
    const float* __restrict__ x,
    const float* __restrict__ Wq, const float* __restrict__ Wk,
    const float* __restrict__ Wv,
    const float* __restrict__ bq, const float* __restrict__ bk,
    const float* __restrict__ bv,
    float* __restrict__ Qb, float* __restrict__ Kb, float* __restrict__ Vb)
{
    const float* W; const float* bias; float* C;
    if (blockIdx.z == 0)      { W = Wq; bias = bq; C = Qb; }
    else if (blockIdx.z == 1) { W = Wk; bias = bk; C = Kb; }
    else                      { W = Wv; bias = bv; C = Vb; }
    gemm_body(x, W, bias, C, BTt, Dd, Dd);
}

__global__ __launch_bounds__(256) void gemm_o(
    const float* __restrict__ A, const float* __restrict__ W,
    const float* __restrict__ bias, float* __restrict__ C)
{
    gemm_body(A, W, bias, C, BTt, Dd, Dd);
}

// ---------------- CoPE attention: one 256-thread block per (b,h,i); LDS-only comm
__global__ __launch_bounds__(256) void cope_attn(
    const float* __restrict__ Q, const float* __restrict__ Kb,
    const float* __restrict__ V, const float* __restrict__ PE,
    float* __restrict__ AO)
{
    const int i = blockIdx.x, h = blockIdx.y, b = blockIdx.z;
    const int t = threadIdx.x;
    const int lane = t & 63, wave = t >> 6;

    __shared__ float q_sh[DHh];
    __shared__ float qpe_sh[MAXPOS];
    __shared__ float qk_sh[Tt];
    __shared__ float gA[Tt];
    __shared__ float gB[Tt];
    __shared__ float p_sh[Tt];
    __shared__ float red[256];
    __shared__ float part[4][DHh];

    const float inv_scale = 0.125f;   // 1/sqrt(64)
    const size_t rowQ = ((size_t)b * Tt + i) * Dd + h * DHh;

    if (t < DHh) q_sh[t] = Q[rowQ + t];
    __syncthreads();

    // qpe table: qpe_sh[p] = q . pos_emb[h][p][:]
    if (t < MAXPOS) {
        const float* pe = &PE[((size_t)h * MAXPOS + t) * DHh];
        float s = 0.f;
        for (int d = 0; d < DHh; ++d) s += q_sh[d] * pe[d];
        qpe_sh[t] = s;
    }

    // qk + gates (thread t owns j = t, t+256, t+512, t+768)
    for (int m = 0; m < 4; ++m) {
        int j = m * 256 + t;
        float s = 0.f;
        if (j <= i) {
            const float* kr = &Kb[((size_t)b * Tt + j) * Dd + h * DHh];
            for (int d = 0; d < DHh; ++d) s += q_sh[d] * kr[d];
        }
        qk_sh[j] = s;
        gA[j] = (j <= i) ? 1.f / (1.f + __expf(-s * inv_scale)) : 0.f;
    }

    // Hillis-Steele inclusive scan over 1024 gates (ping-pong LDS)
    float* cur = gA;
    float* nxt = gB;
    for (int o = 1; o < Tt; o <<= 1) {
        __syncthreads();
        for (int m = 0; m < 4; ++m) {
            int j = m * 256 + t;
            float v = cur[j];
            if (j >= o) v += cur[j - o];
            nxt[j] = v;
        }
        float* tmp = cur; cur = nxt; nxt = tmp;
    }
    __syncthreads();
    const float total = cur[Tt - 1];

    // scores with interpolated CoPE bias + local max
    float sv[4];
    float mloc = -3.0e38f;
    for (int m = 0; m < 4; ++m) {
        int j = m * 256 + t;
        if (j <= i) {
            float pos = total - cur[j];
            pos = fminf(fmaxf(pos, 0.f), 63.f);
            float pf = floorf(pos);
            float a = pos - pf;
            int fi = (int)pf;
            int ci = (int)ceilf(pos);
            if (ci > 63) ci = 63;
            float qpe = (1.f - a) * qpe_sh[fi] + a * qpe_sh[ci];
            sv[m] = (qk_sh[j] + qpe) * inv_scale;
            mloc = fmaxf(mloc, sv[m]);
        } else sv[m] = 0.f;
    }
    red[t] = mloc;
    __syncthreads();
    for (int o = 128; o > 0; o >>= 1) {
        if (t < o) red[t] = fmaxf(red[t], red[t + o]);
        __syncthreads();
    }
    const float Mx = red[0];
    __syncthreads();

    // exp + denom
    float ps = 0.f;
    for (int m = 0; m < 4; ++m) {
        int j = m * 256 + t;
        float p = (j <= i) ? __expf(sv[m] - Mx) : 0.f;
        p_sh[j] = p;
        ps += p;
    }
    red[t] = ps;
    __syncthreads();
    for (int o = 128; o > 0; o >>= 1) {
        if (t < o) red[t] += red[t + o];
        __syncthreads();
    }
    const float denom = red[0];

    // PV: wave w handles j = w, w+4, ...; lane = d (coalesced within wave)
    float acc = 0.f;
    for (int j = wave; j <= i; j += 4)
        acc += p_sh[j] * V[((size_t)b * Tt + j) * Dd + h * DHh + lane];
    part[wave][lane] = acc;
    __syncthreads();
    if (wave == 0) {
        float o2 = (part[0][lane] + part[1][lane] + part[2][lane] + part[3][lane]) / denom;
        AO[rowQ + lane] = o2;
    }
}

// ---------------- launch ---------------------------------------------------------
extern "C" void kernel_launch(void* const* d_in, const int* in_sizes, int n_in,
                              void* d_out, int out_size, void* d_ws, size_t ws_size,
                              hipStream_t stream)
{
    const float* x  = (const float*)d_in[0];
    const float* Wq = (const float*)d_in[1];
    const float* bq = (const float*)d_in[2];
    const float* Wk = (const float*)d_in[3];
    const float* bk = (const float*)d_in[4];
    const float* Wv = (const float*)d_in[5];
    const float* bv = (const float*)d_in[6];
    const float* Wo = (const float*)d_in[7];
    const float* bo = (const float*)d_in[8];
    const float* pe = (const float*)d_in[9];
    // d_in[10]: causal mask (j > i) — structural, unused

    float* Qb = (float*)d_ws;
    float* Kb = Qb + (size_t)BTt * Dd;
    float* Vb = Kb + (size_t)BTt * Dd;
    float* AO = Vb + (size_t)BTt * Dd;

    dim3 gq(BTt / GBM, Dd / GBN, 3);
    gemm_qkv<<<gq, 256, 0, stream>>>(x, Wq, Wk, Wv, bq, bk, bv, Qb, Kb, Vb);

    dim3 ga(Tt, Hh, 2);
    cope_attn<<<ga, 256, 0, stream>>>(Qb, Kb, Vb, pe, AO);

    dim3 go(BTt / GBM, Dd / GBN, 1);
    gemm_o<<<go, 256, 0, stream>>>(AO, Wo, bo, (float*)d_out);
}

// Round 4
// 1030.350 us; speedup vs baseline: 1.4204x; 1.4204x over previous
//
#include <hip/hip_runtime.h>
#include <math.h>

#define Tt 1024
#define Dd 1024
#define Hh 16
#define DHh 64
#define MAXPOS 64
#define BTt 2048

typedef short short8 __attribute__((ext_vector_type(8)));
typedef float floatx4 __attribute__((ext_vector_type(4)));

__device__ __forceinline__ unsigned short f2bf(float f) {
    unsigned u;
    __builtin_memcpy(&u, &f, 4);
    u = (u + 0x7FFFu + ((u >> 16) & 1u)) >> 16;
    return (unsigned short)u;
}

// ------------- MFMA GEMM: C[M,N] = A[M,K] * W[N,K]^T + bias (fp32 I/O, bf16 MFMA)
#define BM 128
#define BN 128
#define BKK 64
#define LDSS 72   // short stride; pad keeps LDS conflicts ~2-way (free)

__device__ __forceinline__ void gemm_body(const float* __restrict__ A,
                                          const float* __restrict__ W,
                                          const float* __restrict__ bias,
                                          float* __restrict__ C,
                                          int M, int N, int K)
{
    __shared__ short Ash[BM * LDSS];
    __shared__ short Bsh[BN * LDSS];
    const int t = threadIdx.x;
    const int lane = t & 63, wave = t >> 6;
    const int wm = wave >> 1, wn = wave & 1;
    const int quad = lane >> 4, l16 = lane & 15;
    const int row0 = blockIdx.x * BM, col0 = blockIdx.y * BN;

    floatx4 acc[4][4];
    for (int a = 0; a < 4; ++a)
        for (int b2 = 0; b2 < 4; ++b2)
            acc[a][b2] = (floatx4){0.f, 0.f, 0.f, 0.f};

    for (int kb = 0; kb < K; kb += BKK) {
        __syncthreads();
        // stage A,B tiles: 128 rows x 64 k, fp32 -> bf16 during staging
        for (int q2 = 0; q2 < 4; ++q2) {
            int ch = t + 256 * q2;          // 0..1023
            int r = ch >> 3, c = ch & 7;    // row, col-chunk (8 elems)
            const float* pA = &A[(size_t)(row0 + r) * K + kb + c * 8];
            const float* pW = &W[(size_t)(col0 + r) * K + kb + c * 8];
            floatx4 a0 = *(const floatx4*)pA;
            floatx4 a1 = *(const floatx4*)(pA + 4);
            floatx4 w0 = *(const floatx4*)pW;
            floatx4 w1 = *(const floatx4*)(pW + 4);
            short8 sa, sw;
            for (int e = 0; e < 4; ++e) {
                sa[e]     = (short)f2bf(a0[e]);
                sa[e + 4] = (short)f2bf(a1[e]);
                sw[e]     = (short)f2bf(w0[e]);
                sw[e + 4] = (short)f2bf(w1[e]);
            }
            *(short8*)&Ash[r * LDSS + c * 8] = sa;
            *(short8*)&Bsh[r * LDSS + c * 8] = sw;
        }
        __syncthreads();
        for (int ks = 0; ks < BKK / 32; ++ks) {
            short8 af[4], bfr[4];
            for (int tm = 0; tm < 4; ++tm)
                af[tm] = *(short8*)&Ash[(wm * 64 + tm * 16 + l16) * LDSS + ks * 32 + quad * 8];
            for (int tn = 0; tn < 4; ++tn)
                bfr[tn] = *(short8*)&Bsh[(wn * 64 + tn * 16 + l16) * LDSS + ks * 32 + quad * 8];
            for (int tm = 0; tm < 4; ++tm)
                for (int tn = 0; tn < 4; ++tn)
                    acc[tm][tn] = __builtin_amdgcn_mfma_f32_16x16x32_bf16(
                        af[tm], bfr[tn], acc[tm][tn], 0, 0, 0);
        }
    }
    // epilogue: C/D layout col=lane&15, row=quad*4+reg
    for (int tm = 0; tm < 4; ++tm)
        for (int tn = 0; tn < 4; ++tn) {
            int col = col0 + wn * 64 + tn * 16 + l16;
            float bv = bias[col];
            for (int r = 0; r < 4; ++r) {
                int row = row0 + wm * 64 + tm * 16 + quad * 4 + r;
                C[(size_t)row * N + col] = acc[tm][tn][r] + bv;
            }
        }
}

__global__ __launch_bounds__(256) void gemm_qkv(
    const float* __restrict__ x,
    const float* __restrict__ Wq, const float* __restrict__ Wk,
    const float* __restrict__ Wv,
    const float* __restrict__ bq, const float* __restrict__ bk,
    const float* __restrict__ bv,
    float* __restrict__ Qb, float* __restrict__ Kb, float* __restrict__ Vb)
{
    const float* W; const float* bias; float* C;
    if (blockIdx.z == 0)      { W = Wq; bias = bq; C = Qb; }
    else if (blockIdx.z == 1) { W = Wk; bias = bk; C = Kb; }
    else                      { W = Wv; bias = bv; C = Vb; }
    gemm_body(x, W, bias, C, BTt, Dd, Dd);
}

__global__ __launch_bounds__(256) void gemm_o(
    const float* __restrict__ A, const float* __restrict__ W,
    const float* __restrict__ bias, float* __restrict__ C)
{
    gemm_body(A, W, bias, C, BTt, Dd, Dd);
}

// ---------------- CoPE attention: one 256-thread block per (b,h,i); LDS-only comm
// (byte-identical to the validated Round-3 kernel)
__global__ __launch_bounds__(256) void cope_attn(
    const float* __restrict__ Q, const float* __restrict__ Kb,
    const float* __restrict__ V, const float* __restrict__ PE,
    float* __restrict__ AO)
{
    const int i = blockIdx.x, h = blockIdx.y, b = blockIdx.z;
    const int t = threadIdx.x;
    const int lane = t & 63, wave = t >> 6;

    __shared__ float q_sh[DHh];
    __shared__ float qpe_sh[MAXPOS];
    __shared__ float qk_sh[Tt];
    __shared__ float gA[Tt];
    __shared__ float gB[Tt];
    __shared__ float p_sh[Tt];
    __shared__ float red[256];
    __shared__ float part[4][DHh];

    const float inv_scale = 0.125f;   // 1/sqrt(64)
    const size_t rowQ = ((size_t)b * Tt + i) * Dd + h * DHh;

    if (t < DHh) q_sh[t] = Q[rowQ + t];
    __syncthreads();

    if (t < MAXPOS) {
        const float* pe = &PE[((size_t)h * MAXPOS + t) * DHh];
        float s = 0.f;
        for (int d = 0; d < DHh; ++d) s += q_sh[d] * pe[d];
        qpe_sh[t] = s;
    }

    for (int m = 0; m < 4; ++m) {
        int j = m * 256 + t;
        float s = 0.f;
        if (j <= i) {
            const float* kr = &Kb[((size_t)b * Tt + j) * Dd + h * DHh];
            for (int d = 0; d < DHh; ++d) s += q_sh[d] * kr[d];
        }
        qk_sh[j] = s;
        gA[j] = (j <= i) ? 1.f / (1.f + __expf(-s * inv_scale)) : 0.f;
    }

    float* cur = gA;
    float* nxt = gB;
    for (int o = 1; o < Tt; o <<= 1) {
        __syncthreads();
        for (int m = 0; m < 4; ++m) {
            int j = m * 256 + t;
            float v = cur[j];
            if (j >= o) v += cur[j - o];
            nxt[j] = v;
        }
        float* tmp = cur; cur = nxt; nxt = tmp;
    }
    __syncthreads();
    const float total = cur[Tt - 1];

    float sv[4];
    float mloc = -3.0e38f;
    for (int m = 0; m < 4; ++m) {
        int j = m * 256 + t;
        if (j <= i) {
            float pos = total - cur[j];
            pos = fminf(fmaxf(pos, 0.f), 63.f);
            float pf = floorf(pos);
            float a = pos - pf;
            int fi = (int)pf;
            int ci = (int)ceilf(pos);
            if (ci > 63) ci = 63;
            float qpe = (1.f - a) * qpe_sh[fi] + a * qpe_sh[ci];
            sv[m] = (qk_sh[j] + qpe) * inv_scale;
            mloc = fmaxf(mloc, sv[m]);
        } else sv[m] = 0.f;
    }
    red[t] = mloc;
    __syncthreads();
    for (int o = 128; o > 0; o >>= 1) {
        if (t < o) red[t] = fmaxf(red[t], red[t + o]);
        __syncthreads();
    }
    const float Mx = red[0];
    __syncthreads();

    float ps = 0.f;
    for (int m = 0; m < 4; ++m) {
        int j = m * 256 + t;
        float p = (j <= i) ? __expf(sv[m] - Mx) : 0.f;
        p_sh[j] = p;
        ps += p;
    }
    red[t] = ps;
    __syncthreads();
    for (int o = 128; o > 0; o >>= 1) {
        if (t < o) red[t] += red[t + o];
        __syncthreads();
    }
    const float denom = red[0];

    float acc = 0.f;
    for (int j = wave; j <= i; j += 4)
        acc += p_sh[j] * V[((size_t)b * Tt + j) * Dd + h * DHh + lane];
    part[wave][lane] = acc;
    __syncthreads();
    if (wave == 0) {
        float o2 = (part[0][lane] + part[1][lane] + part[2][lane] + part[3][lane]) / denom;
        AO[rowQ + lane] = o2;
    }
}

// ---------------- launch ---------------------------------------------------------
extern "C" void kernel_launch(void* const* d_in, const int* in_sizes, int n_in,
                              void* d_out, int out_size, void* d_ws, size_t ws_size,
                              hipStream_t stream)
{
    const float* x  = (const float*)d_in[0];
    const float* Wq = (const float*)d_in[1];
    const float* bq = (const float*)d_in[2];
    const float* Wk = (const float*)d_in[3];
    const float* bk = (const float*)d_in[4];
    const float* Wv = (const float*)d_in[5];
    const float* bv = (const float*)d_in[6];
    const float* Wo = (const float*)d_in[7];
    const float* bo = (const float*)d_in[8];
    const float* pe = (const float*)d_in[9];
    // d_in[10]: causal mask (j > i) — structural, unused

    float* Qb = (float*)d_ws;
    float* Kb = Qb + (size_t)BTt * Dd;
    float* Vb = Kb + (size_t)BTt * Dd;
    float* AO = Vb + (size_t)BTt * Dd;

    dim3 gq(BTt / BM, Dd / BN, 3);
    gemm_qkv<<<gq, 256, 0, stream>>>(x, Wq, Wk, Wv, bq, bk, bv, Qb, Kb, Vb);

    dim3 ga(Tt, Hh, 2);
    cope_attn<<<ga, 256, 0, stream>>>(Qb, Kb, Vb, pe, AO);

    dim3 go(BTt / BM, Dd / BN, 1);
    gemm_o<<<go, 256, 0, stream>>>(AO, Wo, bo, (float*)d_out);
}

// Round 5
// 294.112 us; speedup vs baseline: 4.9760x; 3.5033x over previous
//
#include <hip/hip_runtime.h>
#include <math.h>

#define Tt 1024
#define Dd 1024
#define Hh 16
#define DHh 64
#define MAXPOS 64
#define BTt 2048

typedef short short8 __attribute__((ext_vector_type(8)));
typedef float floatx4 __attribute__((ext_vector_type(4)));

#define MFMA16 __builtin_amdgcn_mfma_f32_16x16x32_bf16

__device__ __forceinline__ unsigned short f2bf(float f) {
    unsigned u;
    __builtin_memcpy(&u, &f, 4);
    u = (u + 0x7FFFu + ((u >> 16) & 1u)) >> 16;
    return (unsigned short)u;
}

// ------------- MFMA GEMM: C = A[M,K] * W[N,K]^T + bias (fp32 in, bf16 MFMA)
// MODE 0: fp32 out row-major. MODE 1: bf16 out row-major. MODE 2: bf16 out
// transposed: Vt[(b*1024 + col)*1024 + (row&1023)]  (b = row>>10)
#define BM 128
#define BN 128
#define BKK 64
#define LDSS 72

template <int MODE>
__device__ __forceinline__ void gemm_body(const float* __restrict__ A,
                                          const float* __restrict__ W,
                                          const float* __restrict__ bias,
                                          void* __restrict__ Cout,
                                          int N, int K)
{
    __shared__ short Ash[BM * LDSS];
    __shared__ short Bsh[BN * LDSS];
    const int t = threadIdx.x;
    const int lane = t & 63, wave = t >> 6;
    const int wm = wave >> 1, wn = wave & 1;
    const int quad = lane >> 4, l16 = lane & 15;
    const int row0 = blockIdx.x * BM, col0 = blockIdx.y * BN;

    floatx4 acc[4][4];
    for (int a = 0; a < 4; ++a)
        for (int b2 = 0; b2 < 4; ++b2)
            acc[a][b2] = (floatx4){0.f, 0.f, 0.f, 0.f};

    for (int kb = 0; kb < K; kb += BKK) {
        __syncthreads();
        for (int q2 = 0; q2 < 4; ++q2) {
            int ch = t + 256 * q2;
            int r = ch >> 3, c = ch & 7;
            const float* pA = &A[(size_t)(row0 + r) * K + kb + c * 8];
            const float* pW = &W[(size_t)(col0 + r) * K + kb + c * 8];
            floatx4 a0 = *(const floatx4*)pA;
            floatx4 a1 = *(const floatx4*)(pA + 4);
            floatx4 w0 = *(const floatx4*)pW;
            floatx4 w1 = *(const floatx4*)(pW + 4);
            short8 sa, sw;
            for (int e = 0; e < 4; ++e) {
                sa[e]     = (short)f2bf(a0[e]);
                sa[e + 4] = (short)f2bf(a1[e]);
                sw[e]     = (short)f2bf(w0[e]);
                sw[e + 4] = (short)f2bf(w1[e]);
            }
            *(short8*)&Ash[r * LDSS + c * 8] = sa;
            *(short8*)&Bsh[r * LDSS + c * 8] = sw;
        }
        __syncthreads();
        for (int ks = 0; ks < BKK / 32; ++ks) {
            short8 af[4], bfr[4];
            for (int tm = 0; tm < 4; ++tm)
                af[tm] = *(short8*)&Ash[(wm * 64 + tm * 16 + l16) * LDSS + ks * 32 + quad * 8];
            for (int tn = 0; tn < 4; ++tn)
                bfr[tn] = *(short8*)&Bsh[(wn * 64 + tn * 16 + l16) * LDSS + ks * 32 + quad * 8];
            for (int tm = 0; tm < 4; ++tm)
                for (int tn = 0; tn < 4; ++tn)
                    acc[tm][tn] = MFMA16(af[tm], bfr[tn], acc[tm][tn], 0, 0, 0);
        }
    }
    for (int tm = 0; tm < 4; ++tm)
        for (int tn = 0; tn < 4; ++tn) {
            int col = col0 + wn * 64 + tn * 16 + l16;
            float bv = bias[col];
            for (int r = 0; r < 4; ++r) {
                int row = row0 + wm * 64 + tm * 16 + quad * 4 + r;
                float v = acc[tm][tn][r] + bv;
                if (MODE == 0) {
                    ((float*)Cout)[(size_t)row * N + col] = v;
                } else if (MODE == 1) {
                    ((short*)Cout)[(size_t)row * N + col] = (short)f2bf(v);
                } else {
                    int b = row >> 10, j = row & 1023;
                    ((short*)Cout)[((size_t)(b * 1024 + col)) * 1024 + j] = (short)f2bf(v);
                }
            }
        }
}

__global__ __launch_bounds__(256) void gemm_qkv(
    const float* __restrict__ x,
    const float* __restrict__ Wq, const float* __restrict__ Wk,
    const float* __restrict__ Wv,
    const float* __restrict__ bq, const float* __restrict__ bk,
    const float* __restrict__ bv,
    short* __restrict__ Qb, short* __restrict__ Kb, short* __restrict__ Vtg)
{
    if (blockIdx.z == 0)      gemm_body<1>(x, Wq, bq, Qb, Dd, Dd);
    else if (blockIdx.z == 1) gemm_body<1>(x, Wk, bk, Kb, Dd, Dd);
    else                      gemm_body<2>(x, Wv, bv, Vtg, Dd, Dd);
}

__global__ __launch_bounds__(256) void gemm_o(
    const float* __restrict__ A, const float* __restrict__ W,
    const float* __restrict__ bias, float* __restrict__ C)
{
    gemm_body<0>(A, W, bias, C, Dd, Dd);
}

// ---------------- Fused CoPE attention: block = (b, h, 32-row Q tile) ----------
// Pass A: per-row gate totals (MFMA QK^T + sigmoid sums).
// Pass B: re-run QK^T tile-by-tile in order; segmented scan w/ carry; CoPE
// interp; online softmax; MFMA PV with V^T from global (pre-transposed).
__global__ __launch_bounds__(256) void cope_attn(
    const short* __restrict__ Q, const short* __restrict__ K,
    const short* __restrict__ Vt, const float* __restrict__ PE,
    float* __restrict__ AO)
{
    const int it = (int)gridDim.x - 1 - (int)blockIdx.x;   // heavy tiles first
    const int h = blockIdx.y, b = blockIdx.z;
    const int i0 = it * 32;
    const int t = threadIdx.x, lane = t & 63, wave = t >> 6;
    const int quad = lane >> 4, l16 = lane & 15;

    __shared__ short Qt[32 * 72];          // A-layout Q tile (bf16)
    __shared__ short KV[128 * 72];         // union: K-tile [128][72] / Vt-tile [64][136] / PE [64][72]
    __shared__ float Sld[32 * 132];        // qk tile, later scores
    __shared__ short Pb[32 * 136];         // P tile (bf16, A-layout)
    __shared__ float qpe[32 * 68];         // q . pos_emb table
    __shared__ float redg[32 * 8], redm[32 * 8], redp[32 * 8];
    __shared__ float tot[32], mrow[32], lrow[32], carry[32], alpha[32];

    const float inv_scale = 0.125f;

    if (t < 32) { tot[t] = 0.f; mrow[t] = -3.0e38f; lrow[t] = 0.f; carry[t] = 0.f; }

    // stage Q tile (bf16 global -> LDS)
    {
        int r = t >> 3, c = t & 7;
        *(short8*)&Qt[r * 72 + c * 8] =
            *(const short8*)&Q[((size_t)(b * Tt + i0 + r)) * Dd + h * DHh + c * 8];
    }
    // stage PE_h (fp32 -> bf16) into KV as [64][72]
    for (int e = 0; e < 16; ++e) {
        int idx = t + 256 * e;
        int p = idx >> 6, d = idx & 63;
        KV[p * 72 + d] = (short)f2bf(PE[((size_t)h * MAXPOS + p) * DHh + d]);
    }
    __syncthreads();

    // qpe[r][p] = Q[r][:] . PE[p][:]  via MFMA (M=32, N=64, K=64)
    {
        int mt = wave >> 1;
        int ntA = 2 * (wave & 1), ntB = ntA + 1;
        floatx4 c0 = {0, 0, 0, 0}, c1 = {0, 0, 0, 0};
        for (int ks = 0; ks < 2; ++ks) {
            short8 a  = *(short8*)&Qt[(mt * 16 + l16) * 72 + ks * 32 + quad * 8];
            short8 b0 = *(short8*)&KV[(ntA * 16 + l16) * 72 + ks * 32 + quad * 8];
            short8 b1 = *(short8*)&KV[(ntB * 16 + l16) * 72 + ks * 32 + quad * 8];
            c0 = MFMA16(a, b0, c0, 0, 0, 0);
            c1 = MFMA16(a, b1, c1, 0, 0, 0);
        }
        for (int r = 0; r < 4; ++r) {
            qpe[(mt * 16 + quad * 4 + r) * 68 + ntA * 16 + l16] = c0[r];
            qpe[(mt * 16 + quad * 4 + r) * 68 + ntB * 16 + l16] = c1[r];
        }
    }

    const int JT = (i0 + 159) >> 7;
    const int sr = t >> 3, ss = t & 7, irow = i0 + sr;

    // ---------------- pass A: per-row gate totals --------------------------------
    for (int jt = 0; jt < JT; ++jt) {
        const int j0 = jt * 128;
        __syncthreads();
        for (int e = 0; e < 4; ++e) {
            int ch = t + 256 * e;
            int jr = ch >> 3, c = ch & 7;
            *(short8*)&KV[jr * 72 + c * 8] =
                *(const short8*)&K[((size_t)(b * Tt + j0 + jr)) * Dd + h * DHh + c * 8];
        }
        __syncthreads();
        {
            int ntA = 2 * wave, ntB = ntA + 1;
            floatx4 c00 = {0,0,0,0}, c01 = {0,0,0,0}, c10 = {0,0,0,0}, c11 = {0,0,0,0};
            for (int ks = 0; ks < 2; ++ks) {
                short8 a0 = *(short8*)&Qt[(l16) * 72 + ks * 32 + quad * 8];
                short8 a1 = *(short8*)&Qt[(16 + l16) * 72 + ks * 32 + quad * 8];
                short8 b0 = *(short8*)&KV[(ntA * 16 + l16) * 72 + ks * 32 + quad * 8];
                short8 b1 = *(short8*)&KV[(ntB * 16 + l16) * 72 + ks * 32 + quad * 8];
                c00 = MFMA16(a0, b0, c00, 0, 0, 0);
                c01 = MFMA16(a0, b1, c01, 0, 0, 0);
                c10 = MFMA16(a1, b0, c10, 0, 0, 0);
                c11 = MFMA16(a1, b1, c11, 0, 0, 0);
            }
            for (int r = 0; r < 4; ++r) {
                Sld[(quad * 4 + r) * 132 + ntA * 16 + l16] = c00[r];
                Sld[(quad * 4 + r) * 132 + ntB * 16 + l16] = c01[r];
                Sld[(16 + quad * 4 + r) * 132 + ntA * 16 + l16] = c10[r];
                Sld[(16 + quad * 4 + r) * 132 + ntB * 16 + l16] = c11[r];
            }
        }
        __syncthreads();
        {
            float gs = 0.f;
            for (int e = 0; e < 16; ++e) {
                int jl = ss * 16 + e, j = j0 + jl;
                if (j <= irow) {
                    float qk = Sld[sr * 132 + jl];
                    gs += 1.f / (1.f + __expf(-qk * inv_scale));
                }
            }
            redg[sr * 8 + ss] = gs;
        }
        __syncthreads();
        if (t < 32) {
            float s2 = 0.f;
            for (int s = 0; s < 8; ++s) s2 += redg[t * 8 + s];
            tot[t] += s2;
        }
    }

    // ---------------- pass B: scores + online softmax + PV -----------------------
    floatx4 o0 = {0, 0, 0, 0}, o1 = {0, 0, 0, 0};
    const int pv_mt = wave >> 1;
    const int pv_ntA = 2 * (wave & 1), pv_ntB = pv_ntA + 1;

    for (int jt = 0; jt < JT; ++jt) {
        const int j0 = jt * 128;
        __syncthreads();                                        // B0
        for (int e = 0; e < 4; ++e) {
            int ch = t + 256 * e;
            int jr = ch >> 3, c = ch & 7;
            *(short8*)&KV[jr * 72 + c * 8] =
                *(const short8*)&K[((size_t)(b * Tt + j0 + jr)) * Dd + h * DHh + c * 8];
        }
        __syncthreads();                                        // B1
        {
            int ntA = 2 * wave, ntB = ntA + 1;
            floatx4 c00 = {0,0,0,0}, c01 = {0,0,0,0}, c10 = {0,0,0,0}, c11 = {0,0,0,0};
            for (int ks = 0; ks < 2; ++ks) {
                short8 a0 = *(short8*)&Qt[(l16) * 72 + ks * 32 + quad * 8];
                short8 a1 = *(short8*)&Qt[(16 + l16) * 72 + ks * 32 + quad * 8];
                short8 b0 = *(short8*)&KV[(ntA * 16 + l16) * 72 + ks * 32 + quad * 8];
                short8 b1 = *(short8*)&KV[(ntB * 16 + l16) * 72 + ks * 32 + quad * 8];
                c00 = MFMA16(a0, b0, c00, 0, 0, 0);
                c01 = MFMA16(a0, b1, c01, 0, 0, 0);
                c10 = MFMA16(a1, b0, c10, 0, 0, 0);
                c11 = MFMA16(a1, b1, c11, 0, 0, 0);
            }
            for (int r = 0; r < 4; ++r) {
                Sld[(quad * 4 + r) * 132 + ntA * 16 + l16] = c00[r];
                Sld[(quad * 4 + r) * 132 + ntB * 16 + l16] = c01[r];
                Sld[(16 + quad * 4 + r) * 132 + ntA * 16 + l16] = c10[r];
                Sld[(16 + quad * 4 + r) * 132 + ntB * 16 + l16] = c11[r];
            }
        }
        __syncthreads();                                        // B2
        // gates into regs + redg; stage V^T tile (K no longer needed)
        float gt[16];
        {
            float gs = 0.f;
            for (int e = 0; e < 16; ++e) {
                int jl = ss * 16 + e, j = j0 + jl;
                float qk = Sld[sr * 132 + jl];
                float g = (j <= irow) ? 1.f / (1.f + __expf(-qk * inv_scale)) : 0.f;
                gt[e] = g;
                gs += g;
            }
            redg[sr * 8 + ss] = gs;
        }
        for (int e = 0; e < 4; ++e) {
            int ch = t + 256 * e;
            int d = ch >> 4, c = ch & 15;
            *(short8*)&KV[d * 136 + c * 8] =
                *(const short8*)&Vt[((size_t)(b * Dd + h * DHh + d)) * Tt + j0 + c * 8];
        }
        __syncthreads();                                        // B3
        // prefix base, scores (overwrite Sld), local max
        {
            float base = carry[sr];
            for (int s2 = 0; s2 < ss; ++s2) base += redg[sr * 8 + s2];
            float run = 0.f, mloc = -3.0e38f;
            float trow = tot[sr];
            for (int e = 0; e < 16; ++e) {
                run += gt[e];
                int jl = ss * 16 + e, j = j0 + jl;
                float qk = Sld[sr * 132 + jl];
                float pos = trow - (base + run);
                pos = fminf(fmaxf(pos, 0.f), 63.f);
                float pf = floorf(pos);
                float al = pos - pf;
                int fi = (int)pf;
                int ci = (int)ceilf(pos);
                if (ci > 63) ci = 63;
                float qp = (1.f - al) * qpe[sr * 68 + fi] + al * qpe[sr * 68 + ci];
                float sc = (j <= irow) ? (qk + qp) * inv_scale : -3.0e38f;
                Sld[sr * 132 + jl] = sc;
                mloc = fmaxf(mloc, sc);
            }
            redm[sr * 8 + ss] = mloc;
        }
        __syncthreads();                                        // B4
        {
            float tm = mrow[sr];
            for (int s2 = 0; s2 < 8; ++s2) tm = fmaxf(tm, redm[sr * 8 + s2]);
            float al_r = __expf(mrow[sr] - tm);
            float psum = 0.f;
            for (int e = 0; e < 16; ++e) {
                int jl = ss * 16 + e, j = j0 + jl;
                float p = (j <= irow) ? __expf(Sld[sr * 132 + jl] - tm) : 0.f;
                Pb[sr * 136 + jl] = (short)f2bf(p);
                psum += p;
            }
            redp[sr * 8 + ss] = psum;
            if (ss == 0) { alpha[sr] = al_r; redm[sr * 8] = tm; }
        }
        __syncthreads();                                        // B5
        if (ss == 0) {
            float ls = 0.f, cs = 0.f;
            for (int s2 = 0; s2 < 8; ++s2) { ls += redp[sr * 8 + s2]; cs += redg[sr * 8 + s2]; }
            lrow[sr] = lrow[sr] * alpha[sr] + ls;
            mrow[sr] = redm[sr * 8];
            carry[sr] += cs;
        }
        // O rescale + MFMA PV (M=32, N=64, K=128)
        {
            for (int r = 0; r < 4; ++r) {
                float a_ = alpha[pv_mt * 16 + quad * 4 + r];
                o0[r] *= a_;
                o1[r] *= a_;
            }
            for (int ks = 0; ks < 4; ++ks) {
                short8 a  = *(short8*)&Pb[(pv_mt * 16 + l16) * 136 + ks * 32 + quad * 8];
                short8 b0 = *(short8*)&KV[(pv_ntA * 16 + l16) * 136 + ks * 32 + quad * 8];
                short8 b1 = *(short8*)&KV[(pv_ntB * 16 + l16) * 136 + ks * 32 + quad * 8];
                o0 = MFMA16(a, b0, o0, 0, 0, 0);
                o1 = MFMA16(a, b1, o1, 0, 0, 0);
            }
        }
    }
    __syncthreads();
    // epilogue: O / l -> AO (fp32)
    for (int r = 0; r < 4; ++r) {
        int row = pv_mt * 16 + quad * 4 + r;
        float inv = 1.f / lrow[row];
        size_t off = ((size_t)(b * Tt + i0 + row)) * Dd + h * DHh;
        AO[off + pv_ntA * 16 + l16] = o0[r] * inv;
        AO[off + pv_ntB * 16 + l16] = o1[r] * inv;
    }
}

// ---------------- launch ---------------------------------------------------------
extern "C" void kernel_launch(void* const* d_in, const int* in_sizes, int n_in,
                              void* d_out, int out_size, void* d_ws, size_t ws_size,
                              hipStream_t stream)
{
    const float* x  = (const float*)d_in[0];
    const float* Wq = (const float*)d_in[1];
    const float* bq = (const float*)d_in[2];
    const float* Wk = (const float*)d_in[3];
    const float* bk = (const float*)d_in[4];
    const float* Wv = (const float*)d_in[5];
    const float* bv = (const float*)d_in[6];
    const float* Wo = (const float*)d_in[7];
    const float* bo = (const float*)d_in[8];
    const float* pe = (const float*)d_in[9];
    // d_in[10]: causal mask (j > i) — structural, unused

    short* Qb  = (short*)d_ws;                       // bf16 [2048][1024]  4 MB
    short* Kb  = Qb + (size_t)BTt * Dd;              // bf16 [2048][1024]  4 MB
    short* Vtg = Kb + (size_t)BTt * Dd;              // bf16 [2][1024][1024] (transposed) 4 MB
    float* AO  = (float*)(Vtg + (size_t)BTt * Dd);   // fp32 [2048][1024]  8 MB

    dim3 gq(BTt / BM, Dd / BN, 3);
    gemm_qkv<<<gq, 256, 0, stream>>>(x, Wq, Wk, Wv, bq, bk, bv, Qb, Kb, Vtg);

    dim3 ga(Tt / 32, Hh, 2);
    cope_attn<<<ga, 256, 0, stream>>>(Qb, Kb, Vtg, pe, AO);

    dim3 go(BTt / BM, Dd / BN, 1);
    gemm_o<<<go, 256, 0, stream>>>(AO, Wo, bo, (float*)d_out);
}

// Round 6
// 258.117 us; speedup vs baseline: 5.6699x; 1.1395x over previous
//
#include <hip/hip_runtime.h>
#include <math.h>

#define Tt 1024
#define Dd 1024
#define Hh 16
#define DHh 64
#define MAXPOS 64
#define BTt 2048

typedef short short8 __attribute__((ext_vector_type(8)));
typedef float floatx4 __attribute__((ext_vector_type(4)));

#define MFMA16 __builtin_amdgcn_mfma_f32_16x16x32_bf16

__device__ __forceinline__ unsigned short f2bf(float f) {
    unsigned u;
    __builtin_memcpy(&u, &f, 4);
    u = (u + 0x7FFFu + ((u >> 16) & 1u)) >> 16;
    return (unsigned short)u;
}

// ---------------- fp32 -> bf16 pre-conversion (x + 4 weights) -------------------
__global__ __launch_bounds__(256) void conv_bf16(
    const float* __restrict__ x,  const float* __restrict__ W0,
    const float* __restrict__ W1, const float* __restrict__ W2,
    const float* __restrict__ W3,
    short* __restrict__ xb, short* __restrict__ w0b, short* __restrict__ w1b,
    short* __restrict__ w2b, short* __restrict__ w3b)
{
    const float* src; short* dst; int n;
    switch (blockIdx.y) {
        case 0:  src = x;  dst = xb;  n = BTt * Dd; break;
        case 1:  src = W0; dst = w0b; n = Dd * Dd;  break;
        case 2:  src = W1; dst = w1b; n = Dd * Dd;  break;
        case 3:  src = W2; dst = w2b; n = Dd * Dd;  break;
        default: src = W3; dst = w3b; n = Dd * Dd;  break;
    }
    int idx = (blockIdx.x * 256 + threadIdx.x) * 8;
    if (idx >= n) return;
    floatx4 a0 = *(const floatx4*)&src[idx];
    floatx4 a1 = *(const floatx4*)&src[idx + 4];
    short8 s;
    for (int e = 0; e < 4; ++e) {
        s[e]     = (short)f2bf(a0[e]);
        s[e + 4] = (short)f2bf(a1[e]);
    }
    *(short8*)&dst[idx] = s;
}

// ------------- MFMA GEMM: C = A[M,K] * W[N,K]^T + bias (bf16 in, bf16 MFMA)
// MODE 0: fp32 out row-major. MODE 1: bf16 out row-major. MODE 2: bf16 out
// transposed: Vt[(b*1024 + col)*1024 + (row&1023)]  (b = row>>10)
#define BM 128
#define BN 128
#define BKK 64
#define LDSS 72

template <int MODE>
__device__ __forceinline__ void gemm_body(const short* __restrict__ A,
                                          const short* __restrict__ W,
                                          const float* __restrict__ bias,
                                          void* __restrict__ Cout,
                                          int N, int K)
{
    __shared__ short Ash[BM * LDSS];
    __shared__ short Bsh[BN * LDSS];
    const int t = threadIdx.x;
    const int lane = t & 63, wave = t >> 6;
    const int wm = wave >> 1, wn = wave & 1;
    const int quad = lane >> 4, l16 = lane & 15;
    const int row0 = blockIdx.x * BM, col0 = blockIdx.y * BN;

    floatx4 acc[4][4];
    for (int a = 0; a < 4; ++a)
        for (int b2 = 0; b2 < 4; ++b2)
            acc[a][b2] = (floatx4){0.f, 0.f, 0.f, 0.f};

    for (int kb = 0; kb < K; kb += BKK) {
        __syncthreads();
        for (int q2 = 0; q2 < 4; ++q2) {
            int ch = t + 256 * q2;
            int r = ch >> 3, c = ch & 7;
            *(short8*)&Ash[r * LDSS + c * 8] =
                *(const short8*)&A[(size_t)(row0 + r) * K + kb + c * 8];
            *(short8*)&Bsh[r * LDSS + c * 8] =
                *(const short8*)&W[(size_t)(col0 + r) * K + kb + c * 8];
        }
        __syncthreads();
        for (int ks = 0; ks < BKK / 32; ++ks) {
            short8 af[4], bfr[4];
            for (int tm = 0; tm < 4; ++tm)
                af[tm] = *(short8*)&Ash[(wm * 64 + tm * 16 + l16) * LDSS + ks * 32 + quad * 8];
            for (int tn = 0; tn < 4; ++tn)
                bfr[tn] = *(short8*)&Bsh[(wn * 64 + tn * 16 + l16) * LDSS + ks * 32 + quad * 8];
            for (int tm = 0; tm < 4; ++tm)
                for (int tn = 0; tn < 4; ++tn)
                    acc[tm][tn] = MFMA16(af[tm], bfr[tn], acc[tm][tn], 0, 0, 0);
        }
    }
    for (int tm = 0; tm < 4; ++tm)
        for (int tn = 0; tn < 4; ++tn) {
            int col = col0 + wn * 64 + tn * 16 + l16;
            float bv = bias[col];
            for (int r = 0; r < 4; ++r) {
                int row = row0 + wm * 64 + tm * 16 + quad * 4 + r;
                float v = acc[tm][tn][r] + bv;
                if (MODE == 0) {
                    ((float*)Cout)[(size_t)row * N + col] = v;
                } else if (MODE == 1) {
                    ((short*)Cout)[(size_t)row * N + col] = (short)f2bf(v);
                } else {
                    int b = row >> 10, j = row & 1023;
                    ((short*)Cout)[((size_t)(b * 1024 + col)) * 1024 + j] = (short)f2bf(v);
                }
            }
        }
}

__global__ __launch_bounds__(256) void gemm_qkv(
    const short* __restrict__ xb,
    const short* __restrict__ Wqb, const short* __restrict__ Wkb,
    const short* __restrict__ Wvb,
    const float* __restrict__ bq, const float* __restrict__ bk,
    const float* __restrict__ bv,
    short* __restrict__ Qb, short* __restrict__ Kb, short* __restrict__ Vtg)
{
    if (blockIdx.z == 0)      gemm_body<1>(xb, Wqb, bq, Qb, Dd, Dd);
    else if (blockIdx.z == 1) gemm_body<1>(xb, Wkb, bk, Kb, Dd, Dd);
    else                      gemm_body<2>(xb, Wvb, bv, Vtg, Dd, Dd);
}

__global__ __launch_bounds__(256) void gemm_o(
    const short* __restrict__ A, const short* __restrict__ W,
    const float* __restrict__ bias, float* __restrict__ C)
{
    gemm_body<0>(A, W, bias, C, Dd, Dd);
}

// ---------------- pass A (parallel): per-(row, j-tile) gate sums ----------------
// grid: (256, Hh, Bb); x encodes it = x>>3 (32 i-tiles), jt = x&7 (8 j-tiles)
__global__ __launch_bounds__(256) void cope_gates(
    const short* __restrict__ Q, const short* __restrict__ K,
    float* __restrict__ gts)
{
    const int xb2 = blockIdx.x;
    const int it = xb2 >> 3, jt = xb2 & 7;
    const int h = blockIdx.y, b = blockIdx.z;
    const int i0 = it * 32, j0 = jt * 128;
    const int t = threadIdx.x, lane = t & 63, wave = t >> 6;
    const int quad = lane >> 4, l16 = lane & 15;

    float* g = &gts[(((size_t)(b * Hh + h)) * Tt + i0) * 8 + jt];
    if (j0 > i0 + 31) {                     // tile fully masked
        if (t < 32) g[t * 8] = 0.f;
        return;
    }

    __shared__ short Qt[32 * 72];
    __shared__ short KV[128 * 72];
    __shared__ float Sld[32 * 132];
    __shared__ float redg[32 * 8];

    const float inv_scale = 0.125f;

    {
        int r = t >> 3, c = t & 7;
        *(short8*)&Qt[r * 72 + c * 8] =
            *(const short8*)&Q[((size_t)(b * Tt + i0 + r)) * Dd + h * DHh + c * 8];
    }
    for (int e = 0; e < 4; ++e) {
        int ch = t + 256 * e;
        int jr = ch >> 3, c = ch & 7;
        *(short8*)&KV[jr * 72 + c * 8] =
            *(const short8*)&K[((size_t)(b * Tt + j0 + jr)) * Dd + h * DHh + c * 8];
    }
    __syncthreads();
    {
        int ntA = 2 * wave, ntB = ntA + 1;
        floatx4 c00 = {0,0,0,0}, c01 = {0,0,0,0}, c10 = {0,0,0,0}, c11 = {0,0,0,0};
        for (int ks = 0; ks < 2; ++ks) {
            short8 a0 = *(short8*)&Qt[(l16) * 72 + ks * 32 + quad * 8];
            short8 a1 = *(short8*)&Qt[(16 + l16) * 72 + ks * 32 + quad * 8];
            short8 b0 = *(short8*)&KV[(ntA * 16 + l16) * 72 + ks * 32 + quad * 8];
            short8 b1 = *(short8*)&KV[(ntB * 16 + l16) * 72 + ks * 32 + quad * 8];
            c00 = MFMA16(a0, b0, c00, 0, 0, 0);
            c01 = MFMA16(a0, b1, c01, 0, 0, 0);
            c10 = MFMA16(a1, b0, c10, 0, 0, 0);
            c11 = MFMA16(a1, b1, c11, 0, 0, 0);
        }
        for (int r = 0; r < 4; ++r) {
            Sld[(quad * 4 + r) * 132 + ntA * 16 + l16] = c00[r];
            Sld[(quad * 4 + r) * 132 + ntB * 16 + l16] = c01[r];
            Sld[(16 + quad * 4 + r) * 132 + ntA * 16 + l16] = c10[r];
            Sld[(16 + quad * 4 + r) * 132 + ntB * 16 + l16] = c11[r];
        }
    }
    __syncthreads();
    {
        const int sr = t >> 3, ss = t & 7, irow = i0 + sr;
        float gs = 0.f;
        for (int e = 0; e < 16; ++e) {
            int jl = ss * 16 + e, j = j0 + jl;
            if (j <= irow) {
                float qk = Sld[sr * 132 + jl];
                gs += 1.f / (1.f + __expf(-qk * inv_scale));
            }
        }
        redg[sr * 8 + ss] = gs;
    }
    __syncthreads();
    if (t < 32) {
        float s2 = 0.f;
        for (int s = 0; s < 8; ++s) s2 += redg[t * 8 + s];
        g[t * 8] = s2;
    }
}

// ---------------- pass B (fused): scores + online softmax + PV ------------------
__global__ __launch_bounds__(256) void cope_attn(
    const short* __restrict__ Q, const short* __restrict__ K,
    const short* __restrict__ Vt, const float* __restrict__ PE,
    const float* __restrict__ gts, short* __restrict__ AOb)
{
    const int it = (int)gridDim.x - 1 - (int)blockIdx.x;   // heavy tiles first
    const int h = blockIdx.y, b = blockIdx.z;
    const int i0 = it * 32;
    const int t = threadIdx.x, lane = t & 63, wave = t >> 6;
    const int quad = lane >> 4, l16 = lane & 15;

    __shared__ short Qt[32 * 72];
    __shared__ short KV[128 * 72];         // K-tile [128][72] / Vt-tile [64][136] / PE [64][72]
    __shared__ float Sld[32 * 132];
    __shared__ short Pb[32 * 136];
    __shared__ float qpe[32 * 68];
    __shared__ float redg[32 * 8], redm[32 * 8], redp[32 * 8];
    __shared__ float gsh[256];
    __shared__ float tot[32], mrow[32], lrow[32], alpha[32];

    const float inv_scale = 0.125f;

    if (t < 32) { mrow[t] = -3.0e38f; lrow[t] = 0.f; }

    gsh[t] = gts[(((size_t)(b * Hh + h)) * Tt + i0 + (t >> 3)) * 8 + (t & 7)];

    {
        int r = t >> 3, c = t & 7;
        *(short8*)&Qt[r * 72 + c * 8] =
            *(const short8*)&Q[((size_t)(b * Tt + i0 + r)) * Dd + h * DHh + c * 8];
    }
    for (int e = 0; e < 16; ++e) {
        int idx = t + 256 * e;
        int p = idx >> 6, d = idx & 63;
        KV[p * 72 + d] = (short)f2bf(PE[((size_t)h * MAXPOS + p) * DHh + d]);
    }
    __syncthreads();

    if (t < 32) {
        float s2 = 0.f;
        for (int k = 0; k < 8; ++k) s2 += gsh[t * 8 + k];
        tot[t] = s2;
    }
    // qpe[r][p] = Q[r][:] . PE[p][:]  via MFMA (M=32, N=64, K=64)
    {
        int mt = wave >> 1;
        int ntA = 2 * (wave & 1), ntB = ntA + 1;
        floatx4 c0 = {0, 0, 0, 0}, c1 = {0, 0, 0, 0};
        for (int ks = 0; ks < 2; ++ks) {
            short8 a  = *(short8*)&Qt[(mt * 16 + l16) * 72 + ks * 32 + quad * 8];
            short8 b0 = *(short8*)&KV[(ntA * 16 + l16) * 72 + ks * 32 + quad * 8];
            short8 b1 = *(short8*)&KV[(ntB * 16 + l16) * 72 + ks * 32 + quad * 8];
            c0 = MFMA16(a, b0, c0, 0, 0, 0);
            c1 = MFMA16(a, b1, c1, 0, 0, 0);
        }
        for (int r = 0; r < 4; ++r) {
            qpe[(mt * 16 + quad * 4 + r) * 68 + ntA * 16 + l16] = c0[r];
            qpe[(mt * 16 + quad * 4 + r) * 68 + ntB * 16 + l16] = c1[r];
        }
    }

    const int JT = (i0 + 159) >> 7;
    const int sr = t >> 3, ss = t & 7, irow = i0 + sr;

    floatx4 o0 = {0, 0, 0, 0}, o1 = {0, 0, 0, 0};
    const int pv_mt = wave >> 1;
    const int pv_ntA = 2 * (wave & 1), pv_ntB = pv_ntA + 1;
    float baseAcc = 0.f;                                    // sum of gts[sr][jt'<jt]

    for (int jt = 0; jt < JT; ++jt) {
        const int j0 = jt * 128;
        __syncthreads();                                    // B0
        for (int e = 0; e < 4; ++e) {
            int ch = t + 256 * e;
            int jr = ch >> 3, c = ch & 7;
            *(short8*)&KV[jr * 72 + c * 8] =
                *(const short8*)&K[((size_t)(b * Tt + j0 + jr)) * Dd + h * DHh + c * 8];
        }
        __syncthreads();                                    // B1
        {
            int ntA = 2 * wave, ntB = ntA + 1;
            floatx4 c00 = {0,0,0,0}, c01 = {0,0,0,0}, c10 = {0,0,0,0}, c11 = {0,0,0,0};
            for (int ks = 0; ks < 2; ++ks) {
                short8 a0 = *(short8*)&Qt[(l16) * 72 + ks * 32 + quad * 8];
                short8 a1 = *(short8*)&Qt[(16 + l16) * 72 + ks * 32 + quad * 8];
                short8 b0 = *(short8*)&KV[(ntA * 16 + l16) * 72 + ks * 32 + quad * 8];
                short8 b1 = *(short8*)&KV[(ntB * 16 + l16) * 72 + ks * 32 + quad * 8];
                c00 = MFMA16(a0, b0, c00, 0, 0, 0);
                c01 = MFMA16(a0, b1, c01, 0, 0, 0);
                c10 = MFMA16(a1, b0, c10, 0, 0, 0);
                c11 = MFMA16(a1, b1, c11, 0, 0, 0);
            }
            for (int r = 0; r < 4; ++r) {
                Sld[(quad * 4 + r) * 132 + ntA * 16 + l16] = c00[r];
                Sld[(quad * 4 + r) * 132 + ntB * 16 + l16] = c01[r];
                Sld[(16 + quad * 4 + r) * 132 + ntA * 16 + l16] = c10[r];
                Sld[(16 + quad * 4 + r) * 132 + ntB * 16 + l16] = c11[r];
            }
        }
        __syncthreads();                                    // B2
        float gt[16];
        {
            float gs = 0.f;
            for (int e = 0; e < 16; ++e) {
                int jl = ss * 16 + e, j = j0 + jl;
                float qk = Sld[sr * 132 + jl];
                float g2 = (j <= irow) ? 1.f / (1.f + __expf(-qk * inv_scale)) : 0.f;
                gt[e] = g2;
                gs += g2;
            }
            redg[sr * 8 + ss] = gs;
        }
        for (int e = 0; e < 4; ++e) {
            int ch = t + 256 * e;
            int d = ch >> 4, c = ch & 15;
            *(short8*)&KV[d * 136 + c * 8] =
                *(const short8*)&Vt[((size_t)(b * Dd + h * DHh + d)) * Tt + j0 + c * 8];
        }
        __syncthreads();                                    // B3
        {
            float base = baseAcc;
            for (int s2 = 0; s2 < ss; ++s2) base += redg[sr * 8 + s2];
            float run = 0.f, mloc = -3.0e38f;
            float trow = tot[sr];
            for (int e = 0; e < 16; ++e) {
                run += gt[e];
                int jl = ss * 16 + e, j = j0 + jl;
                float qk = Sld[sr * 132 + jl];
                float pos = trow - (base + run);
                pos = fminf(fmaxf(pos, 0.f), 63.f);
                float pf = floorf(pos);
                float al = pos - pf;
                int fi = (int)pf;
                int ci = (int)ceilf(pos);
                if (ci > 63) ci = 63;
                float qp = (1.f - al) * qpe[sr * 68 + fi] + al * qpe[sr * 68 + ci];
                float sc = (j <= irow) ? (qk + qp) * inv_scale : -3.0e38f;
                Sld[sr * 132 + jl] = sc;
                mloc = fmaxf(mloc, sc);
            }
            redm[sr * 8 + ss] = mloc;
        }
        __syncthreads();                                    // B4
        {
            float tm = mrow[sr];
            for (int s2 = 0; s2 < 8; ++s2) tm = fmaxf(tm, redm[sr * 8 + s2]);
            float al_r = __expf(mrow[sr] - tm);
            float psum = 0.f;
            for (int e = 0; e < 16; ++e) {
                int jl = ss * 16 + e, j = j0 + jl;
                float p = (j <= irow) ? __expf(Sld[sr * 132 + jl] - tm) : 0.f;
                Pb[sr * 136 + jl] = (short)f2bf(p);
                psum += p;
            }
            redp[sr * 8 + ss] = psum;
            if (ss == 0) { alpha[sr] = al_r; redm[sr * 8] = tm; }
        }
        __syncthreads();                                    // B5
        if (ss == 0) {
            float ls = 0.f;
            for (int s2 = 0; s2 < 8; ++s2) ls += redp[sr * 8 + s2];
            lrow[sr] = lrow[sr] * alpha[sr] + ls;
            mrow[sr] = redm[sr * 8];
        }
        {
            for (int r = 0; r < 4; ++r) {
                float a_ = alpha[pv_mt * 16 + quad * 4 + r];
                o0[r] *= a_;
                o1[r] *= a_;
            }
            for (int ks = 0; ks < 4; ++ks) {
                short8 a  = *(short8*)&Pb[(pv_mt * 16 + l16) * 136 + ks * 32 + quad * 8];
                short8 b0 = *(short8*)&KV[(pv_ntA * 16 + l16) * 136 + ks * 32 + quad * 8];
                short8 b1 = *(short8*)&KV[(pv_ntB * 16 + l16) * 136 + ks * 32 + quad * 8];
                o0 = MFMA16(a, b0, o0, 0, 0, 0);
                o1 = MFMA16(a, b1, o1, 0, 0, 0);
            }
        }
        baseAcc += gsh[sr * 8 + jt];
    }
    __syncthreads();
    for (int r = 0; r < 4; ++r) {
        int row = pv_mt * 16 + quad * 4 + r;
        float inv = 1.f / lrow[row];
        size_t off = ((size_t)(b * Tt + i0 + row)) * Dd + h * DHh;
        AOb[off + pv_ntA * 16 + l16] = (short)f2bf(o0[r] * inv);
        AOb[off + pv_ntB * 16 + l16] = (short)f2bf(o1[r] * inv);
    }
}

// ---------------- launch ---------------------------------------------------------
extern "C" void kernel_launch(void* const* d_in, const int* in_sizes, int n_in,
                              void* d_out, int out_size, void* d_ws, size_t ws_size,
                              hipStream_t stream)
{
    const float* x  = (const float*)d_in[0];
    const float* Wq = (const float*)d_in[1];
    const float* bq = (const float*)d_in[2];
    const float* Wk = (const float*)d_in[3];
    const float* bk = (const float*)d_in[4];
    const float* Wv = (const float*)d_in[5];
    const float* bv = (const float*)d_in[6];
    const float* Wo = (const float*)d_in[7];
    const float* bo = (const float*)d_in[8];
    const float* pe = (const float*)d_in[9];
    // d_in[10]: causal mask (j > i) — structural, unused

    // workspace layout (32 MB total)
    short* xb  = (short*)d_ws;                          //  4 MB bf16 x
    short* Wqb = xb  + (size_t)BTt * Dd;                //  2 MB
    short* Wkb = Wqb + (size_t)Dd * Dd;                 //  2 MB
    short* Wvb = Wkb + (size_t)Dd * Dd;                 //  2 MB
    short* Wob = Wvb + (size_t)Dd * Dd;                 //  2 MB
    short* Qb  = Wob + (size_t)Dd * Dd;                 //  4 MB
    short* Kb  = Qb  + (size_t)BTt * Dd;                //  4 MB
    short* Vtg = Kb  + (size_t)BTt * Dd;                //  4 MB (transposed)
    short* AOb = Vtg + (size_t)BTt * Dd;                //  4 MB
    float* gts = (float*)(AOb + (size_t)BTt * Dd);      //  4 MB [2][16][1024][8]

    dim3 gc(BTt * Dd / 8 / 256, 5);
    conv_bf16<<<gc, 256, 0, stream>>>(x, Wq, Wk, Wv, Wo, xb, Wqb, Wkb, Wvb, Wob);

    dim3 gq(BTt / BM, Dd / BN, 3);
    gemm_qkv<<<gq, 256, 0, stream>>>(xb, Wqb, Wkb, Wvb, bq, bk, bv, Qb, Kb, Vtg);

    dim3 gg(256, Hh, 2);
    cope_gates<<<gg, 256, 0, stream>>>(Qb, Kb, gts);

    dim3 ga(Tt / 32, Hh, 2);
    cope_attn<<<ga, 256, 0, stream>>>(Qb, Kb, Vtg, pe, gts, AOb);

    dim3 go(BTt / BM, Dd / BN, 1);
    gemm_o<<<go, 256, 0, stream>>>(AOb, Wob, bo, (float*)d_out);
}

// Round 7
// 236.716 us; speedup vs baseline: 6.1825x; 1.0904x over previous
//
#include <hip/hip_runtime.h>
#include <math.h>

#define Tt 1024
#define Dd 1024
#define Hh 16
#define DHh 64
#define MAXPOS 64
#define BTt 2048

typedef short short8 __attribute__((ext_vector_type(8)));
typedef float floatx4 __attribute__((ext_vector_type(4)));

#define MFMA16 __builtin_amdgcn_mfma_f32_16x16x32_bf16

__device__ __forceinline__ unsigned short f2bf(float f) {
    unsigned u;
    __builtin_memcpy(&u, &f, 4);
    u = (u + 0x7FFFu + ((u >> 16) & 1u)) >> 16;
    return (unsigned short)u;
}
__device__ __forceinline__ float bf2fs(short s) {
    unsigned u = ((unsigned)(unsigned short)s) << 16;
    float f;
    __builtin_memcpy(&f, &u, 4);
    return f;
}

// ---------------- fp32 -> bf16 pre-conversion (x + 4 weights) -------------------
__global__ __launch_bounds__(256) void conv_bf16(
    const float* __restrict__ x,  const float* __restrict__ W0,
    const float* __restrict__ W1, const float* __restrict__ W2,
    const float* __restrict__ W3,
    short* __restrict__ xb, short* __restrict__ w0b, short* __restrict__ w1b,
    short* __restrict__ w2b, short* __restrict__ w3b)
{
    const float* src; short* dst; int n;
    switch (blockIdx.y) {
        case 0:  src = x;  dst = xb;  n = BTt * Dd; break;
        case 1:  src = W0; dst = w0b; n = Dd * Dd;  break;
        case 2:  src = W1; dst = w1b; n = Dd * Dd;  break;
        case 3:  src = W2; dst = w2b; n = Dd * Dd;  break;
        default: src = W3; dst = w3b; n = Dd * Dd;  break;
    }
    int idx = (blockIdx.x * 256 + threadIdx.x) * 8;
    if (idx >= n) return;
    floatx4 a0 = *(const floatx4*)&src[idx];
    floatx4 a1 = *(const floatx4*)&src[idx + 4];
    short8 s;
    for (int e = 0; e < 4; ++e) {
        s[e]     = (short)f2bf(a0[e]);
        s[e + 4] = (short)f2bf(a1[e]);
    }
    *(short8*)&dst[idx] = s;
}

// ------------- MFMA GEMM: C = A[M,K] * W[N,K]^T + bias (bf16 in, bf16 MFMA)
#define BM 128
#define BN 128
#define BKK 64
#define LDSS 72

template <int MODE>
__device__ __forceinline__ void gemm_body(const short* __restrict__ A,
                                          const short* __restrict__ W,
                                          const float* __restrict__ bias,
                                          void* __restrict__ Cout,
                                          int N, int K)
{
    __shared__ __align__(16) short Ash[BM * LDSS];
    __shared__ __align__(16) short Bsh[BN * LDSS];
    const int t = threadIdx.x;
    const int lane = t & 63, wave = t >> 6;
    const int wm = wave >> 1, wn = wave & 1;
    const int quad = lane >> 4, l16 = lane & 15;
    const int row0 = blockIdx.x * BM, col0 = blockIdx.y * BN;

    floatx4 acc[4][4];
    for (int a = 0; a < 4; ++a)
        for (int b2 = 0; b2 < 4; ++b2)
            acc[a][b2] = (floatx4){0.f, 0.f, 0.f, 0.f};

    for (int kb = 0; kb < K; kb += BKK) {
        __syncthreads();
        for (int q2 = 0; q2 < 4; ++q2) {
            int ch = t + 256 * q2;
            int r = ch >> 3, c = ch & 7;
            *(short8*)&Ash[r * LDSS + c * 8] =
                *(const short8*)&A[(size_t)(row0 + r) * K + kb + c * 8];
            *(short8*)&Bsh[r * LDSS + c * 8] =
                *(const short8*)&W[(size_t)(col0 + r) * K + kb + c * 8];
        }
        __syncthreads();
        for (int ks = 0; ks < BKK / 32; ++ks) {
            short8 af[4], bfr[4];
            for (int tm = 0; tm < 4; ++tm)
                af[tm] = *(short8*)&Ash[(wm * 64 + tm * 16 + l16) * LDSS + ks * 32 + quad * 8];
            for (int tn = 0; tn < 4; ++tn)
                bfr[tn] = *(short8*)&Bsh[(wn * 64 + tn * 16 + l16) * LDSS + ks * 32 + quad * 8];
            for (int tm = 0; tm < 4; ++tm)
                for (int tn = 0; tn < 4; ++tn)
                    acc[tm][tn] = MFMA16(af[tm], bfr[tn], acc[tm][tn], 0, 0, 0);
        }
    }
    for (int tm = 0; tm < 4; ++tm)
        for (int tn = 0; tn < 4; ++tn) {
            int col = col0 + wn * 64 + tn * 16 + l16;
            float bv = bias[col];
            for (int r = 0; r < 4; ++r) {
                int row = row0 + wm * 64 + tm * 16 + quad * 4 + r;
                float v = acc[tm][tn][r] + bv;
                if (MODE == 0) {
                    ((float*)Cout)[(size_t)row * N + col] = v;
                } else if (MODE == 1) {
                    ((short*)Cout)[(size_t)row * N + col] = (short)f2bf(v);
                } else {
                    int b = row >> 10, j = row & 1023;
                    ((short*)Cout)[((size_t)(b * 1024 + col)) * 1024 + j] = (short)f2bf(v);
                }
            }
        }
}

__global__ __launch_bounds__(256) void gemm_qkv(
    const short* __restrict__ xb,
    const short* __restrict__ Wqb, const short* __restrict__ Wkb,
    const short* __restrict__ Wvb,
    const float* __restrict__ bq, const float* __restrict__ bk,
    const float* __restrict__ bv,
    short* __restrict__ Qb, short* __restrict__ Kb, short* __restrict__ Vtg)
{
    if (blockIdx.z == 0)      gemm_body<1>(xb, Wqb, bq, Qb, Dd, Dd);
    else if (blockIdx.z == 1) gemm_body<1>(xb, Wkb, bk, Kb, Dd, Dd);
    else                      gemm_body<2>(xb, Wvb, bv, Vtg, Dd, Dd);
}

__global__ __launch_bounds__(256) void gemm_o(
    const short* __restrict__ A, const short* __restrict__ W,
    const float* __restrict__ bias, float* __restrict__ C)
{
    gemm_body<0>(A, W, bias, C, Dd, Dd);
}

// ---------------- pass A (parallel): per-(row, j-tile) gate sums ----------------
__global__ __launch_bounds__(256) void cope_gates(
    const short* __restrict__ Q, const short* __restrict__ K,
    float* __restrict__ gts)
{
    const int xb2 = blockIdx.x;
    const int it = xb2 >> 3, jt = xb2 & 7;
    const int h = blockIdx.y, b = blockIdx.z;
    const int i0 = it * 32, j0 = jt * 128;
    const int t = threadIdx.x, lane = t & 63, wave = t >> 6;
    const int quad = lane >> 4, l16 = lane & 15;

    float* g = &gts[(((size_t)(b * Hh + h)) * Tt + i0) * 8 + jt];
    if (j0 > i0 + 31) {                     // tile fully masked
        if (t < 32) g[t * 8] = 0.f;
        return;
    }

    __shared__ __align__(16) short Qt[32 * 72];
    __shared__ __align__(16) short KV[128 * 72];
    __shared__ float Sld[32 * 132];
    __shared__ float redg[32 * 8];

    const float inv_scale = 0.125f;

    {
        int r = t >> 3, c = t & 7;
        *(short8*)&Qt[r * 72 + c * 8] =
            *(const short8*)&Q[((size_t)(b * Tt + i0 + r)) * Dd + h * DHh + c * 8];
    }
    for (int e = 0; e < 4; ++e) {
        int ch = t + 256 * e;
        int jr = ch >> 3, c = ch & 7;
        *(short8*)&KV[jr * 72 + c * 8] =
            *(const short8*)&K[((size_t)(b * Tt + j0 + jr)) * Dd + h * DHh + c * 8];
    }
    __syncthreads();
    {
        int ntA = 2 * wave, ntB = ntA + 1;
        floatx4 c00 = {0,0,0,0}, c01 = {0,0,0,0}, c10 = {0,0,0,0}, c11 = {0,0,0,0};
        for (int ks = 0; ks < 2; ++ks) {
            short8 a0 = *(short8*)&Qt[(l16) * 72 + ks * 32 + quad * 8];
            short8 a1 = *(short8*)&Qt[(16 + l16) * 72 + ks * 32 + quad * 8];
            short8 b0 = *(short8*)&KV[(ntA * 16 + l16) * 72 + ks * 32 + quad * 8];
            short8 b1 = *(short8*)&KV[(ntB * 16 + l16) * 72 + ks * 32 + quad * 8];
            c00 = MFMA16(a0, b0, c00, 0, 0, 0);
            c01 = MFMA16(a0, b1, c01, 0, 0, 0);
            c10 = MFMA16(a1, b0, c10, 0, 0, 0);
            c11 = MFMA16(a1, b1, c11, 0, 0, 0);
        }
        for (int r = 0; r < 4; ++r) {
            Sld[(quad * 4 + r) * 132 + ntA * 16 + l16] = c00[r];
            Sld[(quad * 4 + r) * 132 + ntB * 16 + l16] = c01[r];
            Sld[(16 + quad * 4 + r) * 132 + ntA * 16 + l16] = c10[r];
            Sld[(16 + quad * 4 + r) * 132 + ntB * 16 + l16] = c11[r];
        }
    }
    __syncthreads();
    {
        const int sr = t >> 3, ss = t & 7, irow = i0 + sr;
        float gs = 0.f;
        for (int e = 0; e < 16; ++e) {
            int jl = ss * 16 + e, j = j0 + jl;
            if (j <= irow) {
                float qk = Sld[sr * 132 + jl];
                gs += 1.f / (1.f + __expf(-qk * inv_scale));
            }
        }
        redg[sr * 8 + ss] = gs;
    }
    __syncthreads();
    if (t < 32) {
        float s2 = 0.f;
        for (int s = 0; s < 8; ++s) s2 += redg[t * 8 + s];
        g[t * 8] = s2;
    }
}

// ---------------- pass B (fused): scores + no-max softmax + PV ------------------
// 48.5 KB LDS -> 3 blocks/CU; 4 barriers per j-tile; Q frags + gts row in regs.
__global__ __launch_bounds__(256) void cope_attn(
    const short* __restrict__ Q, const short* __restrict__ K,
    const short* __restrict__ Vt, const float* __restrict__ PE,
    const float* __restrict__ gts, short* __restrict__ AOb)
{
    const int it = (int)gridDim.x - 1 - (int)blockIdx.x;   // heavy tiles first
    const int h = blockIdx.y, b = blockIdx.z;
    const int i0 = it * 32;
    const int t = threadIdx.x, lane = t & 63, wave = t >> 6;
    const int quad = lane >> 4, l16 = lane & 15;

    __shared__ __align__(16) float Sld[32 * 132];   // 16896 B (setup: aliased as Q tile)
    __shared__ __align__(16) short KV[128 * 72];    // 18432 B: K[128][72] / V[64][136] / PE[64][72]
    __shared__ __align__(16) short Pb[32 * 136];    // 8704 B
    __shared__ short qpeB[32 * 68];                 // 4352 B (bf16)
    __shared__ float lrow[32];

    const float inv_scale = 0.125f;
    const int sr = t >> 3, ss = t & 7, irow = i0 + sr;

    // gts row for this thread's row -> registers
    float grow[8];
    {
        const float* gp = &gts[(((size_t)(b * Hh + h)) * Tt + i0 + sr) * 8];
        for (int k = 0; k < 8; ++k) grow[k] = gp[k];
    }
    float tot = 0.f;
    for (int k = 0; k < 8; ++k) tot += grow[k];

    // stage Q tile into Sld-alias and PE into KV
    short* QtS = (short*)Sld;
    {
        int r = t >> 3, c = t & 7;
        *(short8*)&QtS[r * 72 + c * 8] =
            *(const short8*)&Q[((size_t)(b * Tt + i0 + r)) * Dd + h * DHh + c * 8];
    }
    for (int e = 0; e < 16; ++e) {
        int idx = t + 256 * e;
        int p = idx >> 6, d = idx & 63;
        KV[p * 72 + d] = (short)f2bf(PE[((size_t)h * MAXPOS + p) * DHh + d]);
    }
    __syncthreads();

    // Q fragments -> registers (rows l16 / 16+l16, ks = 0,1)
    short8 qa[2][2];
    for (int rb = 0; rb < 2; ++rb)
        for (int ks = 0; ks < 2; ++ks)
            qa[rb][ks] = *(short8*)&QtS[(rb * 16 + l16) * 72 + ks * 32 + quad * 8];

    // qpe[r][p] = Q[r] . PE[p] via MFMA (M=32, N=64, K=64) -> bf16 table
    {
        int mt = wave >> 1;
        int ntA = 2 * (wave & 1), ntB = ntA + 1;
        floatx4 c0 = {0, 0, 0, 0}, c1 = {0, 0, 0, 0};
        for (int ks = 0; ks < 2; ++ks) {
            short8 b0 = *(short8*)&KV[(ntA * 16 + l16) * 72 + ks * 32 + quad * 8];
            short8 b1 = *(short8*)&KV[(ntB * 16 + l16) * 72 + ks * 32 + quad * 8];
            c0 = MFMA16(qa[mt][ks], b0, c0, 0, 0, 0);
            c1 = MFMA16(qa[mt][ks], b1, c1, 0, 0, 0);
        }
        for (int r = 0; r < 4; ++r) {
            qpeB[(mt * 16 + quad * 4 + r) * 68 + ntA * 16 + l16] = (short)f2bf(c0[r]);
            qpeB[(mt * 16 + quad * 4 + r) * 68 + ntB * 16 + l16] = (short)f2bf(c1[r]);
        }
    }

    const int JT = (i0 + 159) >> 7;
    floatx4 o0 = {0, 0, 0, 0}, o1 = {0, 0, 0, 0};
    const int pv_mt = wave >> 1;
    const int pv_ntA = 2 * (wave & 1), pv_ntB = pv_ntA + 1;
    float l_acc = 0.f;      // per-thread partial denom for row sr
    float baseAcc = 0.f;    // gate prefix over completed tiles

    for (int jt = 0; jt < JT; ++jt) {
        const int j0 = jt * 128;
        __syncthreads();                                    // A: KV free (qpe/PV done)
        for (int e = 0; e < 4; ++e) {
            int ch = t + 256 * e;
            int jr = ch >> 3, c = ch & 7;
            *(short8*)&KV[jr * 72 + c * 8] =
                *(const short8*)&K[((size_t)(b * Tt + j0 + jr)) * Dd + h * DHh + c * 8];
        }
        __syncthreads();                                    // B: K staged, Sld free
        {
            int ntA = 2 * wave, ntB = ntA + 1;
            floatx4 c00 = {0,0,0,0}, c01 = {0,0,0,0}, c10 = {0,0,0,0}, c11 = {0,0,0,0};
            for (int ks = 0; ks < 2; ++ks) {
                short8 b0 = *(short8*)&KV[(ntA * 16 + l16) * 72 + ks * 32 + quad * 8];
                short8 b1 = *(short8*)&KV[(ntB * 16 + l16) * 72 + ks * 32 + quad * 8];
                c00 = MFMA16(qa[0][ks], b0, c00, 0, 0, 0);
                c01 = MFMA16(qa[0][ks], b1, c01, 0, 0, 0);
                c10 = MFMA16(qa[1][ks], b0, c10, 0, 0, 0);
                c11 = MFMA16(qa[1][ks], b1, c11, 0, 0, 0);
            }
            for (int r = 0; r < 4; ++r) {
                Sld[(quad * 4 + r) * 132 + ntA * 16 + l16] = c00[r];
                Sld[(quad * 4 + r) * 132 + ntB * 16 + l16] = c01[r];
                Sld[(16 + quad * 4 + r) * 132 + ntA * 16 + l16] = c10[r];
                Sld[(16 + quad * 4 + r) * 132 + ntB * 16 + l16] = c11[r];
            }
        }
        __syncthreads();                                    // C: S ready, K reads done
        // stage V (overwrites KV) while computing scores from Sld
        for (int e = 0; e < 4; ++e) {
            int ch = t + 256 * e;
            int d = ch >> 4, c = ch & 15;
            *(short8*)&KV[d * 136 + c * 8] =
                *(const short8*)&Vt[((size_t)(b * Dd + h * DHh + d)) * Tt + j0 + c * 8];
        }
        {
            float qkv_[16], gt[16];
            float gs = 0.f;
            for (int e = 0; e < 16; ++e) {
                int jl = ss * 16 + e, j = j0 + jl;
                float qk = Sld[sr * 132 + jl];
                qkv_[e] = qk;
                float g = (j <= irow) ? 1.f / (1.f + __expf(-qk * inv_scale)) : 0.f;
                gt[e] = g;
                gs += g;
            }
            // 8-lane inclusive scan over ss (aligned groups within wave)
            float inc = gs;
            for (int d2 = 1; d2 < 8; d2 <<= 1) {
                float n = __shfl_up(inc, d2, 64);
                if ((lane & 7) >= d2) inc += n;
            }
            float base = baseAcc + (inc - gs);
            float run = 0.f;
            for (int e = 0; e < 16; ++e) {
                run += gt[e];
                int jl = ss * 16 + e, j = j0 + jl;
                float pos = tot - (base + run);
                pos = fminf(fmaxf(pos, 0.f), 63.f);
                float pf = floorf(pos);
                float al = pos - pf;
                int fi = (int)pf;
                int ci = fi + (al > 0.f ? 1 : 0);
                if (ci > 63) ci = 63;
                float qp = (1.f - al) * bf2fs(qpeB[sr * 68 + fi]) + al * bf2fs(qpeB[sr * 68 + ci]);
                float p = (j <= irow) ? __expf((qkv_[e] + qp) * inv_scale) : 0.f;
                Pb[sr * 136 + jl] = (short)f2bf(p);
                l_acc += p;
            }
            baseAcc += grow[jt];
        }
        __syncthreads();                                    // D: Pb + V ready
        for (int ks = 0; ks < 4; ++ks) {
            short8 a  = *(short8*)&Pb[(pv_mt * 16 + l16) * 136 + ks * 32 + quad * 8];
            short8 b0 = *(short8*)&KV[(pv_ntA * 16 + l16) * 136 + ks * 32 + quad * 8];
            short8 b1 = *(short8*)&KV[(pv_ntB * 16 + l16) * 136 + ks * 32 + quad * 8];
            o0 = MFMA16(a, b0, o0, 0, 0, 0);
            o1 = MFMA16(a, b1, o1, 0, 0, 0);
        }
    }
    // denom: 8-lane butterfly per row group, publish via LDS
    float lr = l_acc;
    for (int d2 = 4; d2 >= 1; d2 >>= 1) lr += __shfl_xor(lr, d2, 64);
    if (ss == 0) lrow[sr] = lr;
    __syncthreads();
    for (int r = 0; r < 4; ++r) {
        int row = pv_mt * 16 + quad * 4 + r;
        float inv = 1.f / lrow[row];
        size_t off = ((size_t)(b * Tt + i0 + row)) * Dd + h * DHh;
        AOb[off + pv_ntA * 16 + l16] = (short)f2bf(o0[r] * inv);
        AOb[off + pv_ntB * 16 + l16] = (short)f2bf(o1[r] * inv);
    }
}

// ---------------- launch ---------------------------------------------------------
extern "C" void kernel_launch(void* const* d_in, const int* in_sizes, int n_in,
                              void* d_out, int out_size, void* d_ws, size_t ws_size,
                              hipStream_t stream)
{
    const float* x  = (const float*)d_in[0];
    const float* Wq = (const float*)d_in[1];
    const float* bq = (const float*)d_in[2];
    const float* Wk = (const float*)d_in[3];
    const float* bk = (const float*)d_in[4];
    const float* Wv = (const float*)d_in[5];
    const float* bv = (const float*)d_in[6];
    const float* Wo = (const float*)d_in[7];
    const float* bo = (const float*)d_in[8];
    const float* pe = (const float*)d_in[9];
    // d_in[10]: causal mask (j > i) — structural, unused

    short* xb  = (short*)d_ws;                          //  4 MB bf16 x
    short* Wqb = xb  + (size_t)BTt * Dd;                //  2 MB
    short* Wkb = Wqb + (size_t)Dd * Dd;                 //  2 MB
    short* Wvb = Wkb + (size_t)Dd * Dd;                 //  2 MB
    short* Wob = Wvb + (size_t)Dd * Dd;                 //  2 MB
    short* Qb  = Wob + (size_t)Dd * Dd;                 //  4 MB
    short* Kb  = Qb  + (size_t)BTt * Dd;                //  4 MB
    short* Vtg = Kb  + (size_t)BTt * Dd;                //  4 MB (transposed)
    short* AOb = Vtg + (size_t)BTt * Dd;                //  4 MB
    float* gts = (float*)(AOb + (size_t)BTt * Dd);      //  4 MB [2][16][1024][8]

    dim3 gc(BTt * Dd / 8 / 256, 5);
    conv_bf16<<<gc, 256, 0, stream>>>(x, Wq, Wk, Wv, Wo, xb, Wqb, Wkb, Wvb, Wob);

    dim3 gq(BTt / BM, Dd / BN, 3);
    gemm_qkv<<<gq, 256, 0, stream>>>(xb, Wqb, Wkb, Wvb, bq, bk, bv, Qb, Kb, Vtg);

    dim3 gg(256, Hh, 2);
    cope_gates<<<gg, 256, 0, stream>>>(Qb, Kb, gts);

    dim3 ga(Tt / 32, Hh, 2);
    cope_attn<<<ga, 256, 0, stream>>>(Qb, Kb, Vtg, pe, gts, AOb);

    dim3 go(BTt / BM, Dd / BN, 1);
    gemm_o<<<go, 256, 0, stream>>>(AOb, Wob, bo, (float*)d_out);
}

// Round 8
// 231.178 us; speedup vs baseline: 6.3306x; 1.0240x over previous
//
#include <hip/hip_runtime.h>
#include <math.h>

#define Tt 1024
#define Dd 1024
#define Hh 16
#define DHh 64
#define MAXPOS 64
#define BTt 2048

typedef short short8 __attribute__((ext_vector_type(8)));
typedef float floatx4 __attribute__((ext_vector_type(4)));

#define MFMA16 __builtin_amdgcn_mfma_f32_16x16x32_bf16

__device__ __forceinline__ unsigned short f2bf(float f) {
    unsigned u;
    __builtin_memcpy(&u, &f, 4);
    u = (u + 0x7FFFu + ((u >> 16) & 1u)) >> 16;
    return (unsigned short)u;
}
__device__ __forceinline__ float bf2fs(short s) {
    unsigned u = ((unsigned)(unsigned short)s) << 16;
    float f;
    __builtin_memcpy(&f, &u, 4);
    return f;
}

// ---------------- fp32 -> bf16 pre-conversion (x + 4 weights) -------------------
__global__ __launch_bounds__(256) void conv_bf16(
    const float* __restrict__ x,  const float* __restrict__ W0,
    const float* __restrict__ W1, const float* __restrict__ W2,
    const float* __restrict__ W3,
    short* __restrict__ xb, short* __restrict__ w0b, short* __restrict__ w1b,
    short* __restrict__ w2b, short* __restrict__ w3b)
{
    const float* src; short* dst; int n;
    switch (blockIdx.y) {
        case 0:  src = x;  dst = xb;  n = BTt * Dd; break;
        case 1:  src = W0; dst = w0b; n = Dd * Dd;  break;
        case 2:  src = W1; dst = w1b; n = Dd * Dd;  break;
        case 3:  src = W2; dst = w2b; n = Dd * Dd;  break;
        default: src = W3; dst = w3b; n = Dd * Dd;  break;
    }
    int idx = (blockIdx.x * 256 + threadIdx.x) * 8;
    if (idx >= n) return;
    floatx4 a0 = *(const floatx4*)&src[idx];
    floatx4 a1 = *(const floatx4*)&src[idx + 4];
    short8 s;
    for (int e = 0; e < 4; ++e) {
        s[e]     = (short)f2bf(a0[e]);
        s[e + 4] = (short)f2bf(a1[e]);
    }
    *(short8*)&dst[idx] = s;
}

// ---------------- bf16 transpose: Vt[b][d][j] = Vrow[b][j][d] -------------------
__global__ __launch_bounds__(256) void vt_trans(
    const short* __restrict__ Vrow, short* __restrict__ Vt)
{
    const int j0 = blockIdx.x * 64, d0 = blockIdx.y * 64, b = blockIdx.z;
    const int t = threadIdx.x;
    __shared__ __align__(16) short L[64 * 72];
    for (int s = 0; s < 2; ++s) {
        int c = t * 2 + s;
        int jr = c >> 3, c8 = c & 7;
        *(short8*)&L[jr * 72 + c8 * 8] =
            *(const short8*)&Vrow[((size_t)(b * Tt + j0 + jr)) * Dd + d0 + c8 * 8];
    }
    __syncthreads();
    for (int s = 0; s < 2; ++s) {
        int c = t * 2 + s;
        int dr = c >> 3, c8 = c & 7;
        short8 v;
        for (int e = 0; e < 8; ++e) v[e] = L[(c8 * 8 + e) * 72 + dr];
        *(short8*)&Vt[((size_t)(b * Dd + d0 + dr)) * Tt + j0 + c8 * 8] = v;
    }
}

// ------------- MFMA GEMM: C = A[M,K] * W[N,K]^T + bias (bf16 in, bf16 MFMA)
#define BM 128
#define BN 128
#define BKK 64
#define LDSS 72

template <int MODE>   // 0: fp32 out, 1: bf16 out
__device__ __forceinline__ void gemm_body(const short* __restrict__ A,
                                          const short* __restrict__ W,
                                          const float* __restrict__ bias,
                                          void* __restrict__ Cout,
                                          int N, int K)
{
    __shared__ __align__(16) short Ash[BM * LDSS];
    __shared__ __align__(16) short Bsh[BN * LDSS];
    const int t = threadIdx.x;
    const int lane = t & 63, wave = t >> 6;
    const int wm = wave >> 1, wn = wave & 1;
    const int quad = lane >> 4, l16 = lane & 15;
    const int row0 = blockIdx.x * BM, col0 = blockIdx.y * BN;

    floatx4 acc[4][4];
    for (int a = 0; a < 4; ++a)
        for (int b2 = 0; b2 < 4; ++b2)
            acc[a][b2] = (floatx4){0.f, 0.f, 0.f, 0.f};

    for (int kb = 0; kb < K; kb += BKK) {
        __syncthreads();
        for (int q2 = 0; q2 < 4; ++q2) {
            int ch = t + 256 * q2;
            int r = ch >> 3, c = ch & 7;
            *(short8*)&Ash[r * LDSS + c * 8] =
                *(const short8*)&A[(size_t)(row0 + r) * K + kb + c * 8];
            *(short8*)&Bsh[r * LDSS + c * 8] =
                *(const short8*)&W[(size_t)(col0 + r) * K + kb + c * 8];
        }
        __syncthreads();
        for (int ks = 0; ks < BKK / 32; ++ks) {
            short8 af[4], bfr[4];
            for (int tm = 0; tm < 4; ++tm)
                af[tm] = *(short8*)&Ash[(wm * 64 + tm * 16 + l16) * LDSS + ks * 32 + quad * 8];
            for (int tn = 0; tn < 4; ++tn)
                bfr[tn] = *(short8*)&Bsh[(wn * 64 + tn * 16 + l16) * LDSS + ks * 32 + quad * 8];
            for (int tm = 0; tm < 4; ++tm)
                for (int tn = 0; tn < 4; ++tn)
                    acc[tm][tn] = MFMA16(af[tm], bfr[tn], acc[tm][tn], 0, 0, 0);
        }
    }
    for (int tm = 0; tm < 4; ++tm)
        for (int tn = 0; tn < 4; ++tn) {
            int col = col0 + wn * 64 + tn * 16 + l16;
            float bv = bias[col];
            for (int r = 0; r < 4; ++r) {
                int row = row0 + wm * 64 + tm * 16 + quad * 4 + r;
                float v = acc[tm][tn][r] + bv;
                if (MODE == 0) ((float*)Cout)[(size_t)row * N + col] = v;
                else           ((short*)Cout)[(size_t)row * N + col] = (short)f2bf(v);
            }
        }
}

__global__ __launch_bounds__(256) void gemm_qkv(
    const short* __restrict__ xb,
    const short* __restrict__ Wqb, const short* __restrict__ Wkb,
    const short* __restrict__ Wvb,
    const float* __restrict__ bq, const float* __restrict__ bk,
    const float* __restrict__ bv,
    short* __restrict__ Qb, short* __restrict__ Kb, short* __restrict__ Vrow)
{
    if (blockIdx.z == 0)      gemm_body<1>(xb, Wqb, bq, Qb, Dd, Dd);
    else if (blockIdx.z == 1) gemm_body<1>(xb, Wkb, bk, Kb, Dd, Dd);
    else                      gemm_body<1>(xb, Wvb, bv, Vrow, Dd, Dd);
}

__global__ __launch_bounds__(256) void gemm_o(
    const short* __restrict__ A, const short* __restrict__ W,
    const float* __restrict__ bias, float* __restrict__ C)
{
    gemm_body<0>(A, W, bias, C, Dd, Dd);
}

// ---------------- pass A (parallel): per-(row, j-tile) gate sums ----------------
__global__ __launch_bounds__(256) void cope_gates(
    const short* __restrict__ Q, const short* __restrict__ K,
    float* __restrict__ gts)
{
    const int xb2 = blockIdx.x;
    const int it = xb2 >> 3, jt = xb2 & 7;
    const int h = blockIdx.y, b = blockIdx.z;
    const int i0 = it * 32, j0 = jt * 128;
    const int t = threadIdx.x, lane = t & 63, wave = t >> 6;
    const int quad = lane >> 4, l16 = lane & 15;

    float* g = &gts[(((size_t)(b * Hh + h)) * Tt + i0) * 8 + jt];
    if (j0 > i0 + 31) {                     // tile fully masked
        if (t < 32) g[t * 8] = 0.f;
        return;
    }

    __shared__ __align__(16) short Qt[32 * 72];
    __shared__ __align__(16) short KV[128 * 72];
    __shared__ float Sld[32 * 132];
    __shared__ float redg[32 * 8];

    const float inv_scale = 0.125f;

    {
        int r = t >> 3, c = t & 7;
        *(short8*)&Qt[r * 72 + c * 8] =
            *(const short8*)&Q[((size_t)(b * Tt + i0 + r)) * Dd + h * DHh + c * 8];
    }
    for (int e = 0; e < 4; ++e) {
        int ch = t + 256 * e;
        int jr = ch >> 3, c = ch & 7;
        *(short8*)&KV[jr * 72 + c * 8] =
            *(const short8*)&K[((size_t)(b * Tt + j0 + jr)) * Dd + h * DHh + c * 8];
    }
    __syncthreads();
    {
        int ntA = 2 * wave, ntB = ntA + 1;
        floatx4 c00 = {0,0,0,0}, c01 = {0,0,0,0}, c10 = {0,0,0,0}, c11 = {0,0,0,0};
        for (int ks = 0; ks < 2; ++ks) {
            short8 a0 = *(short8*)&Qt[(l16) * 72 + ks * 32 + quad * 8];
            short8 a1 = *(short8*)&Qt[(16 + l16) * 72 + ks * 32 + quad * 8];
            short8 b0 = *(short8*)&KV[(ntA * 16 + l16) * 72 + ks * 32 + quad * 8];
            short8 b1 = *(short8*)&KV[(ntB * 16 + l16) * 72 + ks * 32 + quad * 8];
            c00 = MFMA16(a0, b0, c00, 0, 0, 0);
            c01 = MFMA16(a0, b1, c01, 0, 0, 0);
            c10 = MFMA16(a1, b0, c10, 0, 0, 0);
            c11 = MFMA16(a1, b1, c11, 0, 0, 0);
        }
        for (int r = 0; r < 4; ++r) {
            Sld[(quad * 4 + r) * 132 + ntA * 16 + l16] = c00[r];
            Sld[(quad * 4 + r) * 132 + ntB * 16 + l16] = c01[r];
            Sld[(16 + quad * 4 + r) * 132 + ntA * 16 + l16] = c10[r];
            Sld[(16 + quad * 4 + r) * 132 + ntB * 16 + l16] = c11[r];
        }
    }
    __syncthreads();
    {
        const int sr = t >> 3, ss = t & 7, irow = i0 + sr;
        float gs = 0.f;
        for (int e = 0; e < 16; ++e) {
            int jl = ss * 16 + e, j = j0 + jl;
            if (j <= irow) {
                float qk = Sld[sr * 132 + jl];
                gs += 1.f / (1.f + __expf(-qk * inv_scale));
            }
        }
        redg[sr * 8 + ss] = gs;
    }
    __syncthreads();
    if (t < 32) {
        float s2 = 0.f;
        for (int s = 0; s < 8; ++s) s2 += redg[t * 8 + s];
        g[t * 8] = s2;
    }
}

// ---------------- pass B (fused): scores + no-max softmax + PV ------------------
// K prefetched to regs during prior tile's scores phase; V loads issued before
// scores VALU; 48.5 KB LDS (3 blocks/CU), 4 barriers/tile.
__global__ __launch_bounds__(256) void cope_attn(
    const short* __restrict__ Q, const short* __restrict__ K,
    const short* __restrict__ Vt, const float* __restrict__ PE,
    const float* __restrict__ gts, short* __restrict__ AOb)
{
    const int it = (int)gridDim.x - 1 - (int)blockIdx.x;   // heavy tiles first
    const int h = blockIdx.y, b = blockIdx.z;
    const int i0 = it * 32;
    const int t = threadIdx.x, lane = t & 63, wave = t >> 6;
    const int quad = lane >> 4, l16 = lane & 15;

    __shared__ __align__(16) float Sld[32 * 132];   // setup: aliased as Q tile
    __shared__ __align__(16) short KV[128 * 72];    // K[128][72] / V[64][136] / PE[64][72]
    __shared__ __align__(16) short Pb[32 * 136];
    __shared__ short qpeB[32 * 68];
    __shared__ float lrow[32];

    const float inv_scale = 0.125f;
    const int sr = t >> 3, ss = t & 7, irow = i0 + sr;
    const int kjr = t >> 3, kc = t & 7;             // this thread's K-staging slot

    float grow[8];
    {
        const float* gp = &gts[(((size_t)(b * Hh + h)) * Tt + i0 + sr) * 8];
        for (int k = 0; k < 8; ++k) grow[k] = gp[k];
    }
    float tot = 0.f;
    for (int k = 0; k < 8; ++k) tot += grow[k];

    short* QtS = (short*)Sld;
    {
        int r = t >> 3, c = t & 7;
        *(short8*)&QtS[r * 72 + c * 8] =
            *(const short8*)&Q[((size_t)(b * Tt + i0 + r)) * Dd + h * DHh + c * 8];
    }
    for (int e = 0; e < 16; ++e) {
        int idx = t + 256 * e;
        int p = idx >> 6, d = idx & 63;
        KV[p * 72 + d] = (short)f2bf(PE[((size_t)h * MAXPOS + p) * DHh + d]);
    }
    __syncthreads();

    short8 qa[2][2];
    for (int rb = 0; rb < 2; ++rb)
        for (int ks = 0; ks < 2; ++ks)
            qa[rb][ks] = *(short8*)&QtS[(rb * 16 + l16) * 72 + ks * 32 + quad * 8];

    // qpe table via MFMA (M=32, N=64, K=64)
    {
        int mt = wave >> 1;
        int ntA = 2 * (wave & 1), ntB = ntA + 1;
        floatx4 c0 = {0, 0, 0, 0}, c1 = {0, 0, 0, 0};
        for (int ks = 0; ks < 2; ++ks) {
            short8 b0 = *(short8*)&KV[(ntA * 16 + l16) * 72 + ks * 32 + quad * 8];
            short8 b1 = *(short8*)&KV[(ntB * 16 + l16) * 72 + ks * 32 + quad * 8];
            c0 = MFMA16(qa[mt][ks], b0, c0, 0, 0, 0);
            c1 = MFMA16(qa[mt][ks], b1, c1, 0, 0, 0);
        }
        for (int r = 0; r < 4; ++r) {
            qpeB[(mt * 16 + quad * 4 + r) * 68 + ntA * 16 + l16] = (short)f2bf(c0[r]);
            qpeB[(mt * 16 + quad * 4 + r) * 68 + ntB * 16 + l16] = (short)f2bf(c1[r]);
        }
    }

    const int JT = (i0 + 159) >> 7;
    floatx4 o0 = {0, 0, 0, 0}, o1 = {0, 0, 0, 0};
    const int pv_mt = wave >> 1;
    const int pv_ntA = 2 * (wave & 1), pv_ntB = pv_ntA + 1;
    float l_acc = 0.f;
    float baseAcc = 0.f;

    // prefetch K tile 0 into regs
    short8 kreg[4];
    for (int e = 0; e < 4; ++e) {
        int ch = t + 256 * e;
        int jr = ch >> 3, c = ch & 7;
        kreg[e] = *(const short8*)&K[((size_t)(b * Tt + jr)) * Dd + h * DHh + c * 8];
    }

    for (int jt = 0; jt < JT; ++jt) {
        const int j0 = jt * 128;
        __syncthreads();                                    // A: KV free (prev PV done)
        for (int e = 0; e < 4; ++e) {
            int ch = t + 256 * e;
            int jr = ch >> 3, c = ch & 7;
            *(short8*)&KV[jr * 72 + c * 8] = kreg[e];
        }
        __syncthreads();                                    // B: K staged
        {
            int ntA = 2 * wave, ntB = ntA + 1;
            floatx4 c00 = {0,0,0,0}, c01 = {0,0,0,0}, c10 = {0,0,0,0}, c11 = {0,0,0,0};
            for (int ks = 0; ks < 2; ++ks) {
                short8 b0 = *(short8*)&KV[(ntA * 16 + l16) * 72 + ks * 32 + quad * 8];
                short8 b1 = *(short8*)&KV[(ntB * 16 + l16) * 72 + ks * 32 + quad * 8];
                c00 = MFMA16(qa[0][ks], b0, c00, 0, 0, 0);
                c01 = MFMA16(qa[0][ks], b1, c01, 0, 0, 0);
                c10 = MFMA16(qa[1][ks], b0, c10, 0, 0, 0);
                c11 = MFMA16(qa[1][ks], b1, c11, 0, 0, 0);
            }
            for (int r = 0; r < 4; ++r) {
                Sld[(quad * 4 + r) * 132 + ntA * 16 + l16] = c00[r];
                Sld[(quad * 4 + r) * 132 + ntB * 16 + l16] = c01[r];
                Sld[(16 + quad * 4 + r) * 132 + ntA * 16 + l16] = c10[r];
                Sld[(16 + quad * 4 + r) * 132 + ntB * 16 + l16] = c11[r];
            }
        }
        __syncthreads();                                    // C: S ready, K reads done
        // issue V loads (regs) + next-K prefetch, then scores VALU, then V->LDS
        short8 vreg[4];
        for (int e = 0; e < 4; ++e) {
            int ch = t + 256 * e;
            int d = ch >> 4, c = ch & 15;
            vreg[e] = *(const short8*)&Vt[((size_t)(b * Dd + h * DHh + d)) * Tt + j0 + c * 8];
        }
        if (jt + 1 < JT) {
            for (int e = 0; e < 4; ++e) {
                int ch = t + 256 * e;
                int jr = ch >> 3, c = ch & 7;
                kreg[e] = *(const short8*)&K[((size_t)(b * Tt + j0 + 128 + jr)) * Dd + h * DHh + c * 8];
            }
        }
        {
            floatx4 qv[4];
            for (int q4 = 0; q4 < 4; ++q4)
                qv[q4] = *(floatx4*)&Sld[sr * 132 + ss * 16 + q4 * 4];
            float gt[16];
            float gs = 0.f;
            for (int e = 0; e < 16; ++e) {
                int j = j0 + ss * 16 + e;
                float qk = qv[e >> 2][e & 3];
                float g = (j <= irow) ? 1.f / (1.f + __expf(-qk * inv_scale)) : 0.f;
                gt[e] = g;
                gs += g;
            }
            float inc = gs;
            for (int d2 = 1; d2 < 8; d2 <<= 1) {
                float n = __shfl_up(inc, d2, 64);
                if ((lane & 7) >= d2) inc += n;
            }
            float base = baseAcc + (inc - gs);
            float run = 0.f;
            short8 p0, p1;
            for (int e = 0; e < 16; ++e) {
                run += gt[e];
                int j = j0 + ss * 16 + e;
                float pos = tot - (base + run);
                pos = fminf(fmaxf(pos, 0.f), 63.f);
                float pf = floorf(pos);
                float al = pos - pf;
                int fi = (int)pf;
                int ci = fi + (al > 0.f ? 1 : 0);
                if (ci > 63) ci = 63;
                float qp = (1.f - al) * bf2fs(qpeB[sr * 68 + fi]) + al * bf2fs(qpeB[sr * 68 + ci]);
                float qk = qv[e >> 2][e & 3];
                float p = (j <= irow) ? __expf((qk + qp) * inv_scale) : 0.f;
                if (e < 8) p0[e] = (short)f2bf(p); else p1[e - 8] = (short)f2bf(p);
                l_acc += p;
            }
            *(short8*)&Pb[sr * 136 + ss * 16]     = p0;
            *(short8*)&Pb[sr * 136 + ss * 16 + 8] = p1;
            baseAcc += grow[jt];
        }
        for (int e = 0; e < 4; ++e) {
            int ch = t + 256 * e;
            int d = ch >> 4, c = ch & 15;
            *(short8*)&KV[d * 136 + c * 8] = vreg[e];
        }
        __syncthreads();                                    // D: Pb + V ready
        for (int ks = 0; ks < 4; ++ks) {
            short8 a  = *(short8*)&Pb[(pv_mt * 16 + l16) * 136 + ks * 32 + quad * 8];
            short8 b0 = *(short8*)&KV[(pv_ntA * 16 + l16) * 136 + ks * 32 + quad * 8];
            short8 b1 = *(short8*)&KV[(pv_ntB * 16 + l16) * 136 + ks * 32 + quad * 8];
            o0 = MFMA16(a, b0, o0, 0, 0, 0);
            o1 = MFMA16(a, b1, o1, 0, 0, 0);
        }
    }
    float lr = l_acc;
    for (int d2 = 4; d2 >= 1; d2 >>= 1) lr += __shfl_xor(lr, d2, 64);
    if (ss == 0) lrow[sr] = lr;
    __syncthreads();
    for (int r = 0; r < 4; ++r) {
        int row = pv_mt * 16 + quad * 4 + r;
        float inv = 1.f / lrow[row];
        size_t off = ((size_t)(b * Tt + i0 + row)) * Dd + h * DHh;
        AOb[off + pv_ntA * 16 + l16] = (short)f2bf(o0[r] * inv);
        AOb[off + pv_ntB * 16 + l16] = (short)f2bf(o1[r] * inv);
    }
}

// ---------------- launch ---------------------------------------------------------
extern "C" void kernel_launch(void* const* d_in, const int* in_sizes, int n_in,
                              void* d_out, int out_size, void* d_ws, size_t ws_size,
                              hipStream_t stream)
{
    const float* x  = (const float*)d_in[0];
    const float* Wq = (const float*)d_in[1];
    const float* bq = (const float*)d_in[2];
    const float* Wk = (const float*)d_in[3];
    const float* bk = (const float*)d_in[4];
    const float* Wv = (const float*)d_in[5];
    const float* bv = (const float*)d_in[6];
    const float* Wo = (const float*)d_in[7];
    const float* bo = (const float*)d_in[8];
    const float* pe = (const float*)d_in[9];
    // d_in[10]: causal mask (j > i) — structural, unused

    short* xb   = (short*)d_ws;                         //  4 MB
    short* Wqb  = xb   + (size_t)BTt * Dd;              //  2 MB
    short* Wkb  = Wqb  + (size_t)Dd * Dd;               //  2 MB
    short* Wvb  = Wkb  + (size_t)Dd * Dd;               //  2 MB
    short* Wob  = Wvb  + (size_t)Dd * Dd;               //  2 MB
    short* Qb   = Wob  + (size_t)Dd * Dd;               //  4 MB
    short* Kb   = Qb   + (size_t)BTt * Dd;              //  4 MB
    short* Vrow = Kb   + (size_t)BTt * Dd;              //  4 MB (row-major)
    short* Vtg  = Vrow + (size_t)BTt * Dd;              //  4 MB (transposed)
    short* AOb  = Vtg  + (size_t)BTt * Dd;              //  4 MB
    float* gts  = (float*)(AOb + (size_t)BTt * Dd);     //  1 MB

    dim3 gc(BTt * Dd / 8 / 256, 5);
    conv_bf16<<<gc, 256, 0, stream>>>(x, Wq, Wk, Wv, Wo, xb, Wqb, Wkb, Wvb, Wob);

    dim3 gq(BTt / BM, Dd / BN, 3);
    gemm_qkv<<<gq, 256, 0, stream>>>(xb, Wqb, Wkb, Wvb, bq, bk, bv, Qb, Kb, Vrow);

    dim3 gt2(16, 16, 2);
    vt_trans<<<gt2, 256, 0, stream>>>(Vrow, Vtg);

    dim3 gg(256, Hh, 2);
    cope_gates<<<gg, 256, 0, stream>>>(Qb, Kb, gts);

    dim3 ga(Tt / 32, Hh, 2);
    cope_attn<<<ga, 256, 0, stream>>>(Qb, Kb, Vtg, pe, gts, AOb);

    dim3 go(BTt / BM, Dd / BN, 1);
    gemm_o<<<go, 256, 0, stream>>>(AOb, Wob, bo, (float*)d_out);
}